// Round 11
// baseline (724.952 us; speedup 1.0000x reference)
//
#include <hip/hip_runtime.h>
#include <hip/hip_bf16.h>

typedef __hip_bfloat16 bf16;
typedef __attribute__((ext_vector_type(8))) short short8;   // 8 bf16 (4 VGPRs)
typedef __attribute__((ext_vector_type(4))) float f32x4;    // 4 fp32 acc
typedef __attribute__((ext_vector_type(2))) float f32x2;

constexpr int NN = 50000;   // nodes
constexpr int NE = 800000;  // edges
constexpr int IC = 64;      // in channels
constexpr int OC = 128;     // out channels
constexpr int NH = 4;       // heads
constexpr unsigned F32_ONE = 0x3F800000u;

__device__ __forceinline__ float ldf(const void* p, int i, bool f32) {
    return f32 ? ((const float*)p)[i]
               : __bfloat162float(((const bf16*)p)[i]);
}

__device__ __forceinline__ int ld_idx(const void* p, long long i, bool i64) {
    return i64 ? (int)((const long long*)p)[i] : ((const int*)p)[i];
}

// inline edge-index width probe: int64 node indices (<2^31) have zero high words
__device__ __forceinline__ bool probe_i64(const void* ei) {
    const unsigned* u = (const unsigned*)ei;
    return (u[1] | u[3] | u[5] | u[7]) == 0u;
}

// f32 -> bf16 bits (RNE)
__device__ __forceinline__ unsigned f2bu(float x) {
    unsigned u = __float_as_uint(x);
    return (u + 0x7FFFu + ((u >> 16) & 1u)) >> 16;
}

// ---- fp8 e4m3 helpers (HW path with manual fallback) ----------------------
__device__ __forceinline__ unsigned char f32_to_fp8(float x) {
#if __has_builtin(__builtin_amdgcn_cvt_pk_fp8_f32)
    return (unsigned char)(__builtin_amdgcn_cvt_pk_fp8_f32(x, x, 0, false) & 0xFF);
#else
    unsigned bits = __float_as_uint(x);
    unsigned s = bits >> 31;
    float a = fabsf(x);
    if (a >= 448.f) return (unsigned char)((s << 7) | 0x7E);
    if (a < 0.015625f) {
        int m = (int)(a * 512.f + 0.5f);
        if (m >= 8) return (unsigned char)((s << 7) | 0x08);
        return (unsigned char)((s << 7) | m);
    }
    unsigned ab = (bits & 0x7FFFFFFFu) + 0x00080000u;
    int e8 = (int)(ab >> 23) - 127 + 7;
    unsigned m3 = (ab >> 20) & 7u;
    if (e8 >= 16) return (unsigned char)((s << 7) | 0x7E);
    return (unsigned char)((s << 7) | ((unsigned)e8 << 3) | m3);
#endif
}

__device__ __forceinline__ void fp8x4_to_f32(unsigned u, float& f0, float& f1,
                                             float& f2, float& f3) {
#if __has_builtin(__builtin_amdgcn_cvt_pk_f32_fp8)
    f32x2 lo = __builtin_amdgcn_cvt_pk_f32_fp8(u, false);
    f32x2 hi = __builtin_amdgcn_cvt_pk_f32_fp8(u, true);
    f0 = lo[0]; f1 = lo[1]; f2 = hi[0]; f3 = hi[1];
#else
    float r[4];
#pragma unroll
    for (int j = 0; j < 4; ++j) {
        unsigned b = (u >> (8 * j)) & 0xFF;
        unsigned s = b >> 7, e = (b >> 3) & 15, m = b & 7;
        float v = (e == 0) ? (float)m * 0.001953125f
                           : __uint_as_float(((e + 120u) << 23) | (m << 20));
        r[j] = s ? -v : v;
    }
    f0 = r[0]; f1 = r[1]; f2 = r[2]; f3 = r[3];
#endif
}

__device__ __forceinline__ void fp8x2_to_f32(unsigned u, float& f0, float& f1) {
#if __has_builtin(__builtin_amdgcn_cvt_pk_f32_fp8)
    f32x2 lo = __builtin_amdgcn_cvt_pk_f32_fp8(u, false);
    f0 = lo[0]; f1 = lo[1];
#else
    float r[2];
#pragma unroll
    for (int j = 0; j < 2; ++j) {
        unsigned b = (u >> (8 * j)) & 0xFF;
        unsigned s = b >> 7, e = (b >> 3) & 15, m = b & 7;
        float v = (e == 0) ? (float)m * 0.001953125f
                           : __uint_as_float(((e + 120u) << 23) | (m << 20));
        r[j] = s ? -v : v;
    }
    f0 = r[0]; f1 = r[1];
#endif
}

// ---------------------------------------------------------------------------
// prep: fused one-shot conversions + cnt zeroing.
// ---------------------------------------------------------------------------
constexpr int PB_X  = 12500;
constexpr int PB_W  = 160;
constexpr int PB_WO = 64;
constexpr int PB_C  = 196;

__global__ __launch_bounds__(256) void prep(
    const void* __restrict__ x,
    const void* __restrict__ Wq, const void* __restrict__ bq,
    const void* __restrict__ Wk, const void* __restrict__ bk,
    const void* __restrict__ Wv, const void* __restrict__ bv,
    const void* __restrict__ We1, const void* __restrict__ be1,
    const void* __restrict__ We2, const void* __restrict__ be2,
    const void* __restrict__ Wo,  const unsigned* __restrict__ gw,
    bf16* __restrict__ xb, bf16* __restrict__ WcatT, bf16* __restrict__ WoT,
    int* __restrict__ cnt,
    float* __restrict__ be1f, float* __restrict__ We2f, float* __restrict__ be2f,
    float* __restrict__ bcat)
{
    const bool f32 = (gw[0] == F32_ONE);
    int b = blockIdx.x, t = threadIdx.x;
    if (b < PB_X) {
        int i = b * 256 + t;
        if (i < NN * IC) xb[i] = __float2bfloat16(ldf(x, i, f32));
    } else if (b < PB_X + PB_W) {
        int idx = (b - PB_X) * 256 + t;         // n*64 + k
        int n = idx >> 6, k = idx & 63;
        int sel = n >> 7, c = n & 127;
        float v;
        if (sel == 0)      v = ldf(Wq, k * OC + c, f32);
        else if (sel == 1) v = ldf(Wk, k * OC + c, f32);
        else if (sel == 2) v = ldf(Wv, k * OC + c, f32);
        else if (sel == 3) v = ldf(We1, k * OC + c, f32);
        else               v = ldf(We1, (IC + k) * OC + c, f32);
        WcatT[idx] = __float2bfloat16(v);
    } else if (b < PB_X + PB_W + PB_WO) {
        int idx = (b - PB_X - PB_W) * 256 + t;  // n*128 + k
        int n = idx >> 7, k = idx & 127;
        WoT[idx] = __float2bfloat16(ldf(Wo, k * OC + n, f32));
    } else if (b < PB_X + PB_W + PB_WO + PB_C) {
        int i = (b - PB_X - PB_W - PB_WO) * 256 + t;
        if (i < NN) cnt[i] = 0;
    } else {
        if (t < OC) be1f[t] = ldf(be1, t, f32);
        for (int i = t; i < OC * NH; i += 256) We2f[i] = ldf(We2, i, f32);
        if (t < NH) be2f[t] = ldf(be2, t, f32);
        for (int n = t; n < 5 * OC; n += 256) {
            int sel = n >> 7, c = n & 127;
            float bb = 0.f;
            if (sel == 0) bb = ldf(bq, c, f32);
            else if (sel == 1) bb = ldf(bk, c, f32);
            else if (sel == 2) bb = ldf(bv, c, f32);
            bcat[n] = bb;
        }
    }
}

// ---------------------------------------------------------------------------
// CSR build: count -> scan -> fill (sorted by dst). ssrc[pos] = src node.
// ---------------------------------------------------------------------------
__global__ __launch_bounds__(256) void csr_count(
    const void* __restrict__ eia, const void* __restrict__ eib, int split,
    int* __restrict__ cnt)
{
    const bool i64 = probe_i64(eia);
    long long e = (long long)blockIdx.x * 256 + threadIdx.x;
    int d = split ? ld_idx(eib, e, i64) : ld_idx(eia, NE + e, i64);
    atomicAdd(&cnt[d], 1);
}

__global__ __launch_bounds__(1024) void csr_scan(const int* __restrict__ cnt,
                                                 int* __restrict__ rowptr,
                                                 int* __restrict__ cursor)
{
    constexpr int T = 1024;
    constexpr int PER = (NN + T - 1) / T;
    __shared__ int psum[T];
    int t = threadIdx.x;
    int base = t * PER;
    int local = 0;
    for (int j = 0; j < PER; ++j) {
        int idx = base + j;
        if (idx < NN) local += cnt[idx];
    }
    psum[t] = local;
    __syncthreads();
    for (int off = 1; off < T; off <<= 1) {
        int v = (t >= off) ? psum[t - off] : 0;
        __syncthreads();
        psum[t] += v;
        __syncthreads();
    }
    int run = (t == 0) ? 0 : psum[t - 1];
    for (int j = 0; j < PER; ++j) {
        int idx = base + j;
        if (idx < NN) {
            rowptr[idx] = run;
            cursor[idx] = run;
            run += cnt[idx];
        }
    }
    if (t == T - 1) rowptr[NN] = run;
}

__global__ __launch_bounds__(256) void csr_fill(
    const void* __restrict__ eia, const void* __restrict__ eib, int split,
    int* __restrict__ cursor, int* __restrict__ ssrc)
{
    const bool i64 = probe_i64(eia);
    long long e = (long long)blockIdx.x * 256 + threadIdx.x;
    int s = ld_idx(eia, e, i64);
    int d = split ? ld_idx(eib, e, i64) : ld_idx(eia, NE + e, i64);
    int pos = atomicAdd(&cursor[d], 1);
    ssrc[pos] = s;
}

// ---------------------------------------------------------------------------
// node_gemm: D[50000 x 640] = xb @ Wcat + bcat  (MFMA 16x16x32 bf16)
// fp8 outputs: qb_dst row = [q 128B | b 128B], ka_src row = [k 128B | a 128B],
// vf8 row = 128B.
// ---------------------------------------------------------------------------
__global__ __launch_bounds__(256) void node_gemm(
    const bf16* __restrict__ xb, const bf16* __restrict__ WcatT,
    const float* __restrict__ bcat,
    unsigned char* __restrict__ qb_dst, unsigned char* __restrict__ ka_src,
    unsigned char* __restrict__ vf8)
{
    int wave = threadIdx.x >> 6;
    int lane = threadIdx.x & 63;
    int quad = lane >> 4;
    int l16  = lane & 15;
    int row_base = blockIdx.x * 16;
    int m = row_base + l16;

    short8 a0 = *(const short8*)(xb + (size_t)m * IC + quad * 8);
    short8 a1 = *(const short8*)(xb + (size_t)m * IC + 32 + quad * 8);

#pragma unroll
    for (int t = 0; t < 10; ++t) {
        int colbase = wave * 160 + t * 16;
        const bf16* bp = WcatT + (size_t)(colbase + l16) * IC + quad * 8;
        short8 b0 = *(const short8*)(bp);
        short8 b1 = *(const short8*)(bp + 32);
        f32x4 acc = {0.f, 0.f, 0.f, 0.f};
        acc = __builtin_amdgcn_mfma_f32_16x16x32_bf16(a0, b0, acc, 0, 0, 0);
        acc = __builtin_amdgcn_mfma_f32_16x16x32_bf16(a1, b1, acc, 0, 0, 0);

        float bias = bcat[colbase + l16];
        int sel = colbase >> 7;
        int cc  = (colbase & 127) + l16;
#pragma unroll
        for (int r = 0; r < 4; ++r) {
            int node = row_base + quad * 4 + r;
            unsigned char val = f32_to_fp8(acc[r] + bias);
            if (sel == 0)      qb_dst[(size_t)node * 256 + cc] = val;
            else if (sel == 1) ka_src[(size_t)node * 256 + cc] = val;
            else if (sel == 2) vf8[(size_t)node * OC + cc] = val;
            else if (sel == 3) ka_src[(size_t)node * 256 + 128 + cc] = val;
            else               qb_dst[(size_t)node * 256 + 128 + cc] = val;
        }
    }
}

// ---------------------------------------------------------------------------
// edge_gather: FUSED edge logit + softmax-weighted aggregation.
// One wave per dst node. dst row (q|b) loaded once. Per in-edge: gather
// src (k|a) row + v row, compute logit, coef=exp(logit) (unnormalized —
// global softmax max-shift not needed, |logit| small), accumulate
// o += coef*v and s += coef. Writes UNNORMALIZED bf16 agg row + s partial.
// Normalization (per-head scalar 1/s) applied later by norm_agg.
// aggb aliases qb_dst: safe — row n is read only by wave n, before its write.
// ---------------------------------------------------------------------------
__global__ __launch_bounds__(256) void edge_gather(
    const int* __restrict__ rowptr, const int* __restrict__ ssrc,
    const unsigned char* __restrict__ qb_dst, const unsigned char* __restrict__ ka_src,
    const unsigned char* __restrict__ vf8,
    const float* __restrict__ be1f, const float* __restrict__ We2f,
    const float* __restrict__ be2f,
    bf16* __restrict__ aggb, float* __restrict__ spart)
{
    int node = blockIdx.x * 4 + (threadIdx.x >> 6);
    int lane = threadIdx.x & 63;
    int li   = lane & 31;
    int c    = li << 2;
    int j    = li & 3;
    int myh  = lane >> 4;

    // dst row once: lane<32 -> q chunk, lane>=32 -> b chunk
    unsigned drow = *(const unsigned*)(qb_dst + (size_t)node * 256 + lane * 4);
    float d0, d1, d2, d3;
    fp8x4_to_f32(drow, d0, d1, d2, d3);

    float4 vb1 = *(const float4*)(be1f + c);
    float4 w0 = *(const float4*)(We2f + 4 * c);
    float4 w1 = *(const float4*)(We2f + 4 * (c + 1));
    float4 w2 = *(const float4*)(We2f + 4 * (c + 2));
    float4 w3 = *(const float4*)(We2f + 4 * (c + 3));
    float be2h = be2f[myh];

    int beg = rowptr[node], end = rowptr[node + 1];
    float o0 = 0.f, o1 = 0.f, s_acc = 0.f;

    if (beg < end) {
        int sfirst = ssrc[beg];
        unsigned srow_n = *(const unsigned*)(ka_src + (size_t)sfirst * 256 + lane * 4);
        unsigned uv_n   = *(const unsigned short*)(vf8 + (size_t)sfirst * OC + 2 * lane);

        for (int p = beg; p < end; ++p) {
            unsigned srow = srow_n, uv = uv_n;
            if (p + 1 < end) {
                int s2 = ssrc[p + 1];
                srow_n = *(const unsigned*)(ka_src + (size_t)s2 * 256 + lane * 4);
                uv_n   = *(const unsigned short*)(vf8 + (size_t)s2 * OC + 2 * lane);
            }
            float s0, s1, s2f, s3;
            fp8x4_to_f32(srow, s0, s1, s2f, s3);

            // dot (valid on lower half: d=q, s=k)
            float t = d0 * s0 + d1 * s1 + d2 * s2f + d3 * s3;
            t += __shfl_xor(t, 1);
            t += __shfl_xor(t, 2);
            t += __shfl_xor(t, 4);        // lower-half lanes 8h..8h+7 hold t_h

            // gate (valid on upper half: d=b, s=a)
            float h0 = fmaxf(s0 + d0 + vb1.x, 0.f);
            float h1 = fmaxf(s1 + d1 + vb1.y, 0.f);
            float h2 = fmaxf(s2f + d2 + vb1.z, 0.f);
            float h3 = fmaxf(s3 + d3 + vb1.w, 0.f);
            float p0 = h0 * w0.x + h1 * w1.x + h2 * w2.x + h3 * w3.x;
            float p1 = h0 * w0.y + h1 * w1.y + h2 * w2.y + h3 * w3.y;
            float p2 = h0 * w0.z + h1 * w1.z + h2 * w2.z + h3 * w3.z;
            float p3 = h0 * w0.w + h1 * w1.w + h2 * w2.w + h3 * w3.w;
            p0 += __shfl_xor(p0, 1); p1 += __shfl_xor(p1, 1);
            p2 += __shfl_xor(p2, 1); p3 += __shfl_xor(p3, 1);
            p0 += __shfl_xor(p0, 2); p1 += __shfl_xor(p1, 2);
            p2 += __shfl_xor(p2, 2); p3 += __shfl_xor(p3, 2);
            float pj = (j == 0) ? p0 : (j == 1) ? p1 : (j == 2) ? p2 : p3;
            pj += __shfl_xor(pj, 4);
            pj += __shfl_xor(pj, 8);
            pj += __shfl_xor(pj, 16);     // upper-half lane 32+j holds gate_j

            // broadcast own head's logit pieces to every lane
            float tj  = __shfl(t, 8 * myh);        // from lower half
            float pjh = __shfl(pj, 32 + myh);      // from upper half
            float coef = __expf(tj * (pjh + be2h) * 0.17677669529663687f);
            s_acc += coef;

            float v0, v1;
            fp8x2_to_f32(uv, v0, v1);
            o0 = fmaf(coef, v0, o0);
            o1 = fmaf(coef, v1, o1);
        }
    }
    *(unsigned*)(aggb + (size_t)node * OC + 2 * lane) = f2bu(o0) | (f2bu(o1) << 16);
    if ((lane & 15) == 0) spart[node * 4 + myh] = s_acc;
}

// ---------------------------------------------------------------------------
// s_fin: reduce per-node s partials (NN x 4) -> finals[4+h] = 1/s_h
// ---------------------------------------------------------------------------
__global__ __launch_bounds__(256) void s_fin(const float* __restrict__ spart,
                                             float* __restrict__ finals)
{
    int t = threadIdx.x;
    int h = t & 3;
    float s = 0.f;
    for (int n = t >> 2; n < NN; n += 64) s += spart[n * 4 + h];
    __shared__ float sm[256];
    sm[t] = s;
    __syncthreads();
    if (t < 4) {
        float tot = 0.f;
        for (int i = t; i < 256; i += 4) tot += sm[i];
        finals[4 + t] = 1.0f / tot;
    }
}

// ---------------------------------------------------------------------------
// norm_agg: aggb *= 1/s[head]  (in-place, uint = 2 bf16)
// ---------------------------------------------------------------------------
__global__ __launch_bounds__(256) void norm_agg(bf16* __restrict__ aggb,
                                                const float* __restrict__ finals)
{
    int i = blockIdx.x * 256 + threadIdx.x;   // uint index, NN*64 total
    if (i >= NN * 64) return;
    int ch2 = i & 63;                          // uint within row
    float inv = finals[4 + (ch2 >> 4)];
    unsigned u = ((unsigned*)aggb)[i];
    float v0 = __uint_as_float(u << 16) * inv;
    float v1 = __uint_as_float(u & 0xFFFF0000u) * inv;
    ((unsigned*)aggb)[i] = f2bu(v0) | (f2bu(v1) << 16);
}

// ---------------------------------------------------------------------------
// out_gemm: MFMA out GEMM + fused LN.
// ---------------------------------------------------------------------------
__global__ __launch_bounds__(256) void out_gemm(
    const bf16* __restrict__ aggb, const bf16* __restrict__ WoT,
    const void* __restrict__ bo, const void* __restrict__ gamma,
    const void* __restrict__ beta, const unsigned* __restrict__ gw,
    void* __restrict__ out)
{
    const bool f32 = (gw[0] == F32_ONE);
    int wave = threadIdx.x >> 6;
    int lane = threadIdx.x & 63;
    int quad = lane >> 4;
    int l16  = lane & 15;
    int rb = blockIdx.x * 64 + wave * 16;
    int m = rb + l16;
    int ma = (m < NN) ? m : 0;

    short8 a[4];
#pragma unroll
    for (int h = 0; h < 4; ++h)
        a[h] = *(const short8*)(aggb + (size_t)ma * OC + h * 32 + quad * 8);

    float o[8][4];
#pragma unroll
    for (int t = 0; t < 8; ++t) {
        const bf16* bp = WoT + (size_t)(t * 16 + l16) * OC + quad * 8;
        f32x4 acc = {0.f, 0.f, 0.f, 0.f};
#pragma unroll
        for (int h = 0; h < 4; ++h) {
            short8 bfr = *(const short8*)(bp + h * 32);
            acc = __builtin_amdgcn_mfma_f32_16x16x32_bf16(a[h], bfr, acc, 0, 0, 0);
        }
        float bias = ldf(bo, t * 16 + l16, f32);
#pragma unroll
        for (int r = 0; r < 4; ++r) o[t][r] = acc[r] + bias;
    }

#pragma unroll
    for (int r = 0; r < 4; ++r) {
        float s1 = 0.f, s2 = 0.f;
#pragma unroll
        for (int t = 0; t < 8; ++t) { s1 += o[t][r]; s2 += o[t][r] * o[t][r]; }
#pragma unroll
        for (int off = 1; off <= 8; off <<= 1) {
            s1 += __shfl_xor(s1, off);
            s2 += __shfl_xor(s2, off);
        }
        float mu = s1 * (1.0f / OC);
        float var = fmaxf(s2 * (1.0f / OC) - mu * mu, 0.f);
        float rs = rsqrtf(var + 1e-5f);
        int node = rb + quad * 4 + r;
        if (node < NN) {
#pragma unroll
            for (int t = 0; t < 8; ++t) {
                int col = t * 16 + l16;
                float y = (o[t][r] - mu) * rs * ldf(gamma, col, f32) + ldf(beta, col, f32);
                if (f32) ((float*)out)[(size_t)node * OC + col] = y;
                else     ((bf16*)out)[(size_t)node * OC + col] = __float2bfloat16(y);
            }
        }
    }
}

// ---------------------------------------------------------------------------
extern "C" void kernel_launch(void* const* d_in, const int* in_sizes, int n_in,
                              void* d_out, int out_size, void* d_ws, size_t ws_size,
                              hipStream_t stream)
{
    int p = 0;
    const void* x   = d_in[p++];
    const void* eia = d_in[p++];
    const void* eib = eia;
    int split = 0;
    if (n_in >= 17) { eib = d_in[p++]; split = 1; }
    const void* Wq   = d_in[p++];
    const void* bq   = d_in[p++];
    const void* Wk   = d_in[p++];
    const void* bk   = d_in[p++];
    const void* Wv   = d_in[p++];
    const void* bv   = d_in[p++];
    const void* We1  = d_in[p++];
    const void* be1  = d_in[p++];
    const void* We2  = d_in[p++];
    const void* be2  = d_in[p++];
    const void* Wo   = d_in[p++];
    const void* bo   = d_in[p++];
    const void* gamma= d_in[p++];
    const void* beta = d_in[p++];
    const unsigned* gw = (const unsigned*)gamma;

    // workspace layout (~44 MB):
    char* w = (char*)d_ws;
    bf16*  xb     = (bf16*)w;                  w += (size_t)NN * IC * 2;  // 6.4 MB
    unsigned char* qb_dst = (unsigned char*)w; w += (size_t)NN * 256;     // 12.8 MB
    unsigned char* ka_src = (unsigned char*)w; w += (size_t)NN * 256;     // 12.8 MB
    unsigned char* vf8    = (unsigned char*)w; w += (size_t)NN * OC;      // 6.4 MB
    int*   ssrc   = (int*)w;                   w += (size_t)NE * 4;       // 3.2 MB
    int*   cnt    = (int*)w;                   w += (size_t)NN * 4;
    int*   rowptr = (int*)w;                   w += (size_t)(NN + 1) * 4;
    int*   cursor = (int*)w;                   w += (size_t)NN * 4;
    float* spart  = (float*)w;                 w += (size_t)NN * 4 * 4;   // 800 KB
    float* finals = (float*)w;                 w += 8 * 4;
    float* be1f   = (float*)w;                 w += OC * 4;
    float* We2f   = (float*)w;                 w += OC * NH * 4;
    float* be2f   = (float*)w;                 w += NH * 4;
    bf16*  WcatT  = (bf16*)w;                  w += (size_t)5 * OC * IC * 2;
    float* bcat   = (float*)w;                 w += 5 * OC * 4;
    bf16*  WoT    = (bf16*)w;                  w += (size_t)OC * OC * 2;

    // alias: aggb over qb_dst (row n read only by wave n before its write)
    bf16*  aggb   = (bf16*)qb_dst;

    if (ws_size < (size_t)((char*)w - (char*)d_ws)) return;

    prep<<<PB_X + PB_W + PB_WO + PB_C + 1, 256, 0, stream>>>(
        x, Wq, bq, Wk, bk, Wv, bv, We1, be1, We2, be2, Wo, gw,
        xb, WcatT, WoT, cnt, be1f, We2f, be2f, bcat);
    csr_count<<<NE / 256, 256, 0, stream>>>(eia, eib, split, cnt);
    csr_scan<<<1, 1024, 0, stream>>>(cnt, rowptr, cursor);
    csr_fill<<<NE / 256, 256, 0, stream>>>(eia, eib, split, cursor, ssrc);
    node_gemm<<<NN / 16, 256, 0, stream>>>(xb, WcatT, bcat, qb_dst, ka_src, vf8);
    edge_gather<<<NN / 4, 256, 0, stream>>>(rowptr, ssrc, qb_dst, ka_src, vf8,
                                            be1f, We2f, be2f, aggb, spart);
    s_fin<<<1, 256, 0, stream>>>(spart, finals);
    norm_agg<<<(NN * 64 + 255) / 256, 256, 0, stream>>>(aggb, finals);
    out_gemm<<<(NN + 63) / 64, 256, 0, stream>>>(aggb, WoT, bo, gamma, beta, gw, d_out);
}

// Round 12
// 540.718 us; speedup vs baseline: 1.3407x; 1.3407x over previous
//
#include <hip/hip_runtime.h>
#include <hip/hip_bf16.h>

typedef __hip_bfloat16 bf16;
typedef __attribute__((ext_vector_type(8))) short short8;   // 8 bf16 (4 VGPRs)
typedef __attribute__((ext_vector_type(4))) float f32x4;    // 4 fp32 acc
typedef __attribute__((ext_vector_type(2))) float f32x2;

constexpr int NN = 50000;   // nodes
constexpr int NE = 800000;  // edges
constexpr int IC = 64;      // in channels
constexpr int OC = 128;     // out channels
constexpr int NH = 4;       // heads
constexpr unsigned F32_ONE = 0x3F800000u;

__device__ __forceinline__ float ldf(const void* p, int i, bool f32) {
    return f32 ? ((const float*)p)[i]
               : __bfloat162float(((const bf16*)p)[i]);
}

__device__ __forceinline__ int ld_idx(const void* p, long long i, bool i64) {
    return i64 ? (int)((const long long*)p)[i] : ((const int*)p)[i];
}

// inline edge-index width probe: int64 node indices (<2^31) have zero high words
__device__ __forceinline__ bool probe_i64(const void* ei) {
    const unsigned* u = (const unsigned*)ei;
    return (u[1] | u[3] | u[5] | u[7]) == 0u;
}

// f32 -> bf16 bits (RNE)
__device__ __forceinline__ unsigned f2bu(float x) {
    unsigned u = __float_as_uint(x);
    return (u + 0x7FFFu + ((u >> 16) & 1u)) >> 16;
}

// ---- fp8 e4m3 helpers (HW path with manual fallback) ----------------------
__device__ __forceinline__ unsigned char f32_to_fp8(float x) {
#if __has_builtin(__builtin_amdgcn_cvt_pk_fp8_f32)
    return (unsigned char)(__builtin_amdgcn_cvt_pk_fp8_f32(x, x, 0, false) & 0xFF);
#else
    unsigned bits = __float_as_uint(x);
    unsigned s = bits >> 31;
    float a = fabsf(x);
    if (a >= 448.f) return (unsigned char)((s << 7) | 0x7E);
    if (a < 0.015625f) {
        int m = (int)(a * 512.f + 0.5f);
        if (m >= 8) return (unsigned char)((s << 7) | 0x08);
        return (unsigned char)((s << 7) | m);
    }
    unsigned ab = (bits & 0x7FFFFFFFu) + 0x00080000u;
    int e8 = (int)(ab >> 23) - 127 + 7;
    unsigned m3 = (ab >> 20) & 7u;
    if (e8 >= 16) return (unsigned char)((s << 7) | 0x7E);
    return (unsigned char)((s << 7) | ((unsigned)e8 << 3) | m3);
#endif
}

__device__ __forceinline__ void fp8x4_to_f32(unsigned u, float& f0, float& f1,
                                             float& f2, float& f3) {
#if __has_builtin(__builtin_amdgcn_cvt_pk_f32_fp8)
    f32x2 lo = __builtin_amdgcn_cvt_pk_f32_fp8(u, false);
    f32x2 hi = __builtin_amdgcn_cvt_pk_f32_fp8(u, true);
    f0 = lo[0]; f1 = lo[1]; f2 = hi[0]; f3 = hi[1];
#else
    float r[4];
#pragma unroll
    for (int j = 0; j < 4; ++j) {
        unsigned b = (u >> (8 * j)) & 0xFF;
        unsigned s = b >> 7, e = (b >> 3) & 15, m = b & 7;
        float v = (e == 0) ? (float)m * 0.001953125f
                           : __uint_as_float(((e + 120u) << 23) | (m << 20));
        r[j] = s ? -v : v;
    }
    f0 = r[0]; f1 = r[1]; f2 = r[2]; f3 = r[3];
#endif
}

__device__ __forceinline__ void fp8x2_to_f32(unsigned u, float& f0, float& f1) {
#if __has_builtin(__builtin_amdgcn_cvt_pk_f32_fp8)
    f32x2 lo = __builtin_amdgcn_cvt_pk_f32_fp8(u, false);
    f0 = lo[0]; f1 = lo[1];
#else
    float r[2];
#pragma unroll
    for (int j = 0; j < 2; ++j) {
        unsigned b = (u >> (8 * j)) & 0xFF;
        unsigned s = b >> 7, e = (b >> 3) & 15, m = b & 7;
        float v = (e == 0) ? (float)m * 0.001953125f
                           : __uint_as_float(((e + 120u) << 23) | (m << 20));
        r[j] = s ? -v : v;
    }
    f0 = r[0]; f1 = r[1];
#endif
}

// ---------------------------------------------------------------------------
// prep: fused one-shot conversions + cnt zeroing + ssum zeroing.
// ---------------------------------------------------------------------------
constexpr int PB_X  = 12500;
constexpr int PB_W  = 160;
constexpr int PB_WO = 64;
constexpr int PB_C  = 196;

__global__ __launch_bounds__(256) void prep(
    const void* __restrict__ x,
    const void* __restrict__ Wq, const void* __restrict__ bq,
    const void* __restrict__ Wk, const void* __restrict__ bk,
    const void* __restrict__ Wv, const void* __restrict__ bv,
    const void* __restrict__ We1, const void* __restrict__ be1,
    const void* __restrict__ We2, const void* __restrict__ be2,
    const void* __restrict__ Wo,  const unsigned* __restrict__ gw,
    bf16* __restrict__ xb, bf16* __restrict__ WcatT, bf16* __restrict__ WoT,
    int* __restrict__ cnt,
    float* __restrict__ be1f, float* __restrict__ We2f, float* __restrict__ be2f,
    float* __restrict__ bcat, float* __restrict__ ssum)
{
    const bool f32 = (gw[0] == F32_ONE);
    int b = blockIdx.x, t = threadIdx.x;
    if (b < PB_X) {
        int i = b * 256 + t;
        if (i < NN * IC) xb[i] = __float2bfloat16(ldf(x, i, f32));
    } else if (b < PB_X + PB_W) {
        int idx = (b - PB_X) * 256 + t;         // n*64 + k
        int n = idx >> 6, k = idx & 63;
        int sel = n >> 7, c = n & 127;
        float v;
        if (sel == 0)      v = ldf(Wq, k * OC + c, f32);
        else if (sel == 1) v = ldf(Wk, k * OC + c, f32);
        else if (sel == 2) v = ldf(Wv, k * OC + c, f32);
        else if (sel == 3) v = ldf(We1, k * OC + c, f32);
        else               v = ldf(We1, (IC + k) * OC + c, f32);
        WcatT[idx] = __float2bfloat16(v);
    } else if (b < PB_X + PB_W + PB_WO) {
        int idx = (b - PB_X - PB_W) * 256 + t;  // n*128 + k
        int n = idx >> 7, k = idx & 127;
        WoT[idx] = __float2bfloat16(ldf(Wo, k * OC + n, f32));
    } else if (b < PB_X + PB_W + PB_WO + PB_C) {
        int i = (b - PB_X - PB_W - PB_WO) * 256 + t;
        if (i < NN) cnt[i] = 0;
    } else {
        if (t < OC) be1f[t] = ldf(be1, t, f32);
        for (int i = t; i < OC * NH; i += 256) We2f[i] = ldf(We2, i, f32);
        if (t < NH) be2f[t] = ldf(be2, t, f32);
        if (t < NH) ssum[t] = 0.f;
        for (int n = t; n < 5 * OC; n += 256) {
            int sel = n >> 7, c = n & 127;
            float bb = 0.f;
            if (sel == 0) bb = ldf(bq, c, f32);
            else if (sel == 1) bb = ldf(bk, c, f32);
            else if (sel == 2) bb = ldf(bv, c, f32);
            bcat[n] = bb;
        }
    }
}

// ---------------------------------------------------------------------------
// CSR build: count -> scan -> fill (sorted by dst). ssrc[pos] = src node.
// ---------------------------------------------------------------------------
__global__ __launch_bounds__(256) void csr_count(
    const void* __restrict__ eia, const void* __restrict__ eib, int split,
    int* __restrict__ cnt)
{
    const bool i64 = probe_i64(eia);
    long long e = (long long)blockIdx.x * 256 + threadIdx.x;
    int d = split ? ld_idx(eib, e, i64) : ld_idx(eia, NE + e, i64);
    atomicAdd(&cnt[d], 1);
}

__global__ __launch_bounds__(1024) void csr_scan(const int* __restrict__ cnt,
                                                 int* __restrict__ rowptr,
                                                 int* __restrict__ cursor)
{
    constexpr int T = 1024;
    constexpr int PER = (NN + T - 1) / T;
    __shared__ int psum[T];
    int t = threadIdx.x;
    int base = t * PER;
    int local = 0;
    for (int j = 0; j < PER; ++j) {
        int idx = base + j;
        if (idx < NN) local += cnt[idx];
    }
    psum[t] = local;
    __syncthreads();
    for (int off = 1; off < T; off <<= 1) {
        int v = (t >= off) ? psum[t - off] : 0;
        __syncthreads();
        psum[t] += v;
        __syncthreads();
    }
    int run = (t == 0) ? 0 : psum[t - 1];
    for (int j = 0; j < PER; ++j) {
        int idx = base + j;
        if (idx < NN) {
            rowptr[idx] = run;
            cursor[idx] = run;
            run += cnt[idx];
        }
    }
    if (t == T - 1) rowptr[NN] = run;
}

__global__ __launch_bounds__(256) void csr_fill(
    const void* __restrict__ eia, const void* __restrict__ eib, int split,
    int* __restrict__ cursor, int* __restrict__ ssrc)
{
    const bool i64 = probe_i64(eia);
    long long e = (long long)blockIdx.x * 256 + threadIdx.x;
    int s = ld_idx(eia, e, i64);
    int d = split ? ld_idx(eib, e, i64) : ld_idx(eia, NE + e, i64);
    int pos = atomicAdd(&cursor[d], 1);
    ssrc[pos] = s;
}

// ---------------------------------------------------------------------------
// node_gemm: D[50000 x 640] = xb @ Wcat + bcat  (MFMA 16x16x32 bf16)
// fp8 outputs: qb_dst row = [q 128B | b 128B], ka_src row = [k 128B | a 128B],
// vf8 row = 128B.
// ---------------------------------------------------------------------------
__global__ __launch_bounds__(256) void node_gemm(
    const bf16* __restrict__ xb, const bf16* __restrict__ WcatT,
    const float* __restrict__ bcat,
    unsigned char* __restrict__ qb_dst, unsigned char* __restrict__ ka_src,
    unsigned char* __restrict__ vf8)
{
    int wave = threadIdx.x >> 6;
    int lane = threadIdx.x & 63;
    int quad = lane >> 4;
    int l16  = lane & 15;
    int row_base = blockIdx.x * 16;
    int m = row_base + l16;

    short8 a0 = *(const short8*)(xb + (size_t)m * IC + quad * 8);
    short8 a1 = *(const short8*)(xb + (size_t)m * IC + 32 + quad * 8);

#pragma unroll
    for (int t = 0; t < 10; ++t) {
        int colbase = wave * 160 + t * 16;
        const bf16* bp = WcatT + (size_t)(colbase + l16) * IC + quad * 8;
        short8 b0 = *(const short8*)(bp);
        short8 b1 = *(const short8*)(bp + 32);
        f32x4 acc = {0.f, 0.f, 0.f, 0.f};
        acc = __builtin_amdgcn_mfma_f32_16x16x32_bf16(a0, b0, acc, 0, 0, 0);
        acc = __builtin_amdgcn_mfma_f32_16x16x32_bf16(a1, b1, acc, 0, 0, 0);

        float bias = bcat[colbase + l16];
        int sel = colbase >> 7;
        int cc  = (colbase & 127) + l16;
#pragma unroll
        for (int r = 0; r < 4; ++r) {
            int node = row_base + quad * 4 + r;
            unsigned char val = f32_to_fp8(acc[r] + bias);
            if (sel == 0)      qb_dst[(size_t)node * 256 + cc] = val;
            else if (sel == 1) ka_src[(size_t)node * 256 + cc] = val;
            else if (sel == 2) vf8[(size_t)node * OC + cc] = val;
            else if (sel == 3) ka_src[(size_t)node * 256 + 128 + cc] = val;
            else               qb_dst[(size_t)node * 256 + 128 + cc] = val;
        }
    }
}

// ---------------------------------------------------------------------------
// edge_gather: FUSED edge logit + softmax-weighted aggregation.
// One wave per dst node; unnormalized coef=exp(logit); agg + s partials.
// ---------------------------------------------------------------------------
__global__ __launch_bounds__(256) void edge_gather(
    const int* __restrict__ rowptr, const int* __restrict__ ssrc,
    const unsigned char* __restrict__ qb_dst, const unsigned char* __restrict__ ka_src,
    const unsigned char* __restrict__ vf8,
    const float* __restrict__ be1f, const float* __restrict__ We2f,
    const float* __restrict__ be2f,
    bf16* __restrict__ aggb, float* __restrict__ spart)
{
    int node = blockIdx.x * 4 + (threadIdx.x >> 6);
    int lane = threadIdx.x & 63;
    int li   = lane & 31;
    int c    = li << 2;
    int j    = li & 3;
    int myh  = lane >> 4;

    // dst row once: lane<32 -> q chunk, lane>=32 -> b chunk
    unsigned drow = *(const unsigned*)(qb_dst + (size_t)node * 256 + lane * 4);
    float d0, d1, d2, d3;
    fp8x4_to_f32(drow, d0, d1, d2, d3);

    float4 vb1 = *(const float4*)(be1f + c);
    float4 w0 = *(const float4*)(We2f + 4 * c);
    float4 w1 = *(const float4*)(We2f + 4 * (c + 1));
    float4 w2 = *(const float4*)(We2f + 4 * (c + 2));
    float4 w3 = *(const float4*)(We2f + 4 * (c + 3));
    float be2h = be2f[myh];

    int beg = rowptr[node], end = rowptr[node + 1];
    float o0 = 0.f, o1 = 0.f, s_acc = 0.f;

    if (beg < end) {
        int sfirst = ssrc[beg];
        unsigned srow_n = *(const unsigned*)(ka_src + (size_t)sfirst * 256 + lane * 4);
        unsigned uv_n   = *(const unsigned short*)(vf8 + (size_t)sfirst * OC + 2 * lane);

        for (int p = beg; p < end; ++p) {
            unsigned srow = srow_n, uv = uv_n;
            if (p + 1 < end) {
                int s2 = ssrc[p + 1];
                srow_n = *(const unsigned*)(ka_src + (size_t)s2 * 256 + lane * 4);
                uv_n   = *(const unsigned short*)(vf8 + (size_t)s2 * OC + 2 * lane);
            }
            float s0, s1, s2f, s3;
            fp8x4_to_f32(srow, s0, s1, s2f, s3);

            // dot (valid on lower half: d=q, s=k)
            float t = d0 * s0 + d1 * s1 + d2 * s2f + d3 * s3;
            t += __shfl_xor(t, 1);
            t += __shfl_xor(t, 2);
            t += __shfl_xor(t, 4);        // lower-half lanes 8h..8h+7 hold t_h

            // gate (valid on upper half: d=b, s=a)
            float h0 = fmaxf(s0 + d0 + vb1.x, 0.f);
            float h1 = fmaxf(s1 + d1 + vb1.y, 0.f);
            float h2 = fmaxf(s2f + d2 + vb1.z, 0.f);
            float h3 = fmaxf(s3 + d3 + vb1.w, 0.f);
            float p0 = h0 * w0.x + h1 * w1.x + h2 * w2.x + h3 * w3.x;
            float p1 = h0 * w0.y + h1 * w1.y + h2 * w2.y + h3 * w3.y;
            float p2 = h0 * w0.z + h1 * w1.z + h2 * w2.z + h3 * w3.z;
            float p3 = h0 * w0.w + h1 * w1.w + h2 * w2.w + h3 * w3.w;
            p0 += __shfl_xor(p0, 1); p1 += __shfl_xor(p1, 1);
            p2 += __shfl_xor(p2, 1); p3 += __shfl_xor(p3, 1);
            p0 += __shfl_xor(p0, 2); p1 += __shfl_xor(p1, 2);
            p2 += __shfl_xor(p2, 2); p3 += __shfl_xor(p3, 2);
            float pj = (j == 0) ? p0 : (j == 1) ? p1 : (j == 2) ? p2 : p3;
            pj += __shfl_xor(pj, 4);
            pj += __shfl_xor(pj, 8);
            pj += __shfl_xor(pj, 16);     // upper-half lane 32+j holds gate_j

            // broadcast own head's logit pieces to every lane
            float tj  = __shfl(t, 8 * myh);        // from lower half
            float pjh = __shfl(pj, 32 + myh);      // from upper half
            float coef = __expf(tj * (pjh + be2h) * 0.17677669529663687f);
            s_acc += coef;

            float v0, v1;
            fp8x2_to_f32(uv, v0, v1);
            o0 = fmaf(coef, v0, o0);
            o1 = fmaf(coef, v1, o1);
        }
    }
    *(unsigned*)(aggb + (size_t)node * OC + 2 * lane) = f2bu(o0) | (f2bu(o1) << 16);
    if ((lane & 15) == 0) spart[node * 4 + myh] = s_acc;
}

// ---------------------------------------------------------------------------
// s_reduce: PARALLEL reduction of spart (NN*4) -> ssum[4] via atomics.
// Grid-stride; each thread's head index is fixed (stride % 4 == 0).
// ---------------------------------------------------------------------------
constexpr int SR_BLOCKS = 98;
__global__ __launch_bounds__(256) void s_reduce(const float* __restrict__ spart,
                                                float* __restrict__ ssum)
{
    int tid = blockIdx.x * 256 + threadIdx.x;
    int h = threadIdx.x & 3;                 // fixed per thread
    float s = 0.f;
    for (int i = tid; i < NN * 4; i += SR_BLOCKS * 256) s += spart[i];
    // lanes sharing h are every 4th lane: reduce over xor 4,8,16,32
#pragma unroll
    for (int off = 4; off <= 32; off <<= 1) s += __shfl_xor(s, off);
    __shared__ float sm[4][4];               // [wave][h]
    int lane = threadIdx.x & 63, w = threadIdx.x >> 6;
    if (lane < 4) sm[w][h] = s;              // lanes 0..3 hold h=0..3 totals
    __syncthreads();
    if (threadIdx.x < 4) {
        float tot = sm[0][h] + sm[1][h] + sm[2][h] + sm[3][h];
        atomicAdd(&ssum[h], tot);
    }
}

// ---------------------------------------------------------------------------
// norm_agg: aggb *= 1/ssum[head]  (in-place, uint = 2 bf16)
// ---------------------------------------------------------------------------
__global__ __launch_bounds__(256) void norm_agg(bf16* __restrict__ aggb,
                                                const float* __restrict__ ssum)
{
    int i = blockIdx.x * 256 + threadIdx.x;   // uint index, NN*64 total
    if (i >= NN * 64) return;
    int ch2 = i & 63;                          // uint within row
    float inv = 1.0f / ssum[ch2 >> 4];
    unsigned u = ((unsigned*)aggb)[i];
    float v0 = __uint_as_float(u << 16) * inv;
    float v1 = __uint_as_float(u & 0xFFFF0000u) * inv;
    ((unsigned*)aggb)[i] = f2bu(v0) | (f2bu(v1) << 16);
}

// ---------------------------------------------------------------------------
// out_gemm: MFMA out GEMM + fused LN.
// ---------------------------------------------------------------------------
__global__ __launch_bounds__(256) void out_gemm(
    const bf16* __restrict__ aggb, const bf16* __restrict__ WoT,
    const void* __restrict__ bo, const void* __restrict__ gamma,
    const void* __restrict__ beta, const unsigned* __restrict__ gw,
    void* __restrict__ out)
{
    const bool f32 = (gw[0] == F32_ONE);
    int wave = threadIdx.x >> 6;
    int lane = threadIdx.x & 63;
    int quad = lane >> 4;
    int l16  = lane & 15;
    int rb = blockIdx.x * 64 + wave * 16;
    int m = rb + l16;
    int ma = (m < NN) ? m : 0;

    short8 a[4];
#pragma unroll
    for (int h = 0; h < 4; ++h)
        a[h] = *(const short8*)(aggb + (size_t)ma * OC + h * 32 + quad * 8);

    float o[8][4];
#pragma unroll
    for (int t = 0; t < 8; ++t) {
        const bf16* bp = WoT + (size_t)(t * 16 + l16) * OC + quad * 8;
        f32x4 acc = {0.f, 0.f, 0.f, 0.f};
#pragma unroll
        for (int h = 0; h < 4; ++h) {
            short8 bfr = *(const short8*)(bp + h * 32);
            acc = __builtin_amdgcn_mfma_f32_16x16x32_bf16(a[h], bfr, acc, 0, 0, 0);
        }
        float bias = ldf(bo, t * 16 + l16, f32);
#pragma unroll
        for (int r = 0; r < 4; ++r) o[t][r] = acc[r] + bias;
    }

#pragma unroll
    for (int r = 0; r < 4; ++r) {
        float s1 = 0.f, s2 = 0.f;
#pragma unroll
        for (int t = 0; t < 8; ++t) { s1 += o[t][r]; s2 += o[t][r] * o[t][r]; }
#pragma unroll
        for (int off = 1; off <= 8; off <<= 1) {
            s1 += __shfl_xor(s1, off);
            s2 += __shfl_xor(s2, off);
        }
        float mu = s1 * (1.0f / OC);
        float var = fmaxf(s2 * (1.0f / OC) - mu * mu, 0.f);
        float rs = rsqrtf(var + 1e-5f);
        int node = rb + quad * 4 + r;
        if (node < NN) {
#pragma unroll
            for (int t = 0; t < 8; ++t) {
                int col = t * 16 + l16;
                float y = (o[t][r] - mu) * rs * ldf(gamma, col, f32) + ldf(beta, col, f32);
                if (f32) ((float*)out)[(size_t)node * OC + col] = y;
                else     ((bf16*)out)[(size_t)node * OC + col] = __float2bfloat16(y);
            }
        }
    }
}

// ---------------------------------------------------------------------------
extern "C" void kernel_launch(void* const* d_in, const int* in_sizes, int n_in,
                              void* d_out, int out_size, void* d_ws, size_t ws_size,
                              hipStream_t stream)
{
    int p = 0;
    const void* x   = d_in[p++];
    const void* eia = d_in[p++];
    const void* eib = eia;
    int split = 0;
    if (n_in >= 17) { eib = d_in[p++]; split = 1; }
    const void* Wq   = d_in[p++];
    const void* bq   = d_in[p++];
    const void* Wk   = d_in[p++];
    const void* bk   = d_in[p++];
    const void* Wv   = d_in[p++];
    const void* bv   = d_in[p++];
    const void* We1  = d_in[p++];
    const void* be1  = d_in[p++];
    const void* We2  = d_in[p++];
    const void* be2  = d_in[p++];
    const void* Wo   = d_in[p++];
    const void* bo   = d_in[p++];
    const void* gamma= d_in[p++];
    const void* beta = d_in[p++];
    const unsigned* gw = (const unsigned*)gamma;

    // workspace layout (~44 MB):
    char* w = (char*)d_ws;
    bf16*  xb     = (bf16*)w;                  w += (size_t)NN * IC * 2;  // 6.4 MB
    unsigned char* qb_dst = (unsigned char*)w; w += (size_t)NN * 256;     // 12.8 MB
    unsigned char* ka_src = (unsigned char*)w; w += (size_t)NN * 256;     // 12.8 MB
    unsigned char* vf8    = (unsigned char*)w; w += (size_t)NN * OC;      // 6.4 MB
    int*   ssrc   = (int*)w;                   w += (size_t)NE * 4;       // 3.2 MB
    int*   cnt    = (int*)w;                   w += (size_t)NN * 4;
    int*   rowptr = (int*)w;                   w += (size_t)(NN + 1) * 4;
    int*   cursor = (int*)w;                   w += (size_t)NN * 4;
    float* spart  = (float*)w;                 w += (size_t)NN * 4 * 4;   // 800 KB
    float* ssum   = (float*)w;                 w += 8 * 4;
    float* be1f   = (float*)w;                 w += OC * 4;
    float* We2f   = (float*)w;                 w += OC * NH * 4;
    float* be2f   = (float*)w;                 w += NH * 4;
    bf16*  WcatT  = (bf16*)w;                  w += (size_t)5 * OC * IC * 2;
    float* bcat   = (float*)w;                 w += 5 * OC * 4;
    bf16*  WoT    = (bf16*)w;                  w += (size_t)OC * OC * 2;

    // alias: aggb over qb_dst (row n read only by wave n before its write)
    bf16*  aggb   = (bf16*)qb_dst;

    if (ws_size < (size_t)((char*)w - (char*)d_ws)) return;

    prep<<<PB_X + PB_W + PB_WO + PB_C + 1, 256, 0, stream>>>(
        x, Wq, bq, Wk, bk, Wv, bv, We1, be1, We2, be2, Wo, gw,
        xb, WcatT, WoT, cnt, be1f, We2f, be2f, bcat, ssum);
    csr_count<<<NE / 256, 256, 0, stream>>>(eia, eib, split, cnt);
    csr_scan<<<1, 1024, 0, stream>>>(cnt, rowptr, cursor);
    csr_fill<<<NE / 256, 256, 0, stream>>>(eia, eib, split, cursor, ssrc);
    node_gemm<<<NN / 16, 256, 0, stream>>>(xb, WcatT, bcat, qb_dst, ka_src, vf8);
    edge_gather<<<NN / 4, 256, 0, stream>>>(rowptr, ssrc, qb_dst, ka_src, vf8,
                                            be1f, We2f, be2f, aggb, spart);
    s_reduce<<<SR_BLOCKS, 256, 0, stream>>>(spart, ssum);
    norm_agg<<<(NN * 64 + 255) / 256, 256, 0, stream>>>(aggb, ssum);
    out_gemm<<<(NN + 63) / 64, 256, 0, stream>>>(aggb, WoT, bo, gamma, beta, gw, d_out);
}

// Round 13
// 520.563 us; speedup vs baseline: 1.3926x; 1.0387x over previous
//
#include <hip/hip_runtime.h>
#include <hip/hip_bf16.h>

typedef __hip_bfloat16 bf16;
typedef __attribute__((ext_vector_type(8))) short short8;   // 8 bf16 (4 VGPRs)
typedef __attribute__((ext_vector_type(4))) float f32x4;    // 4 fp32 acc
typedef __attribute__((ext_vector_type(2))) float f32x2;

constexpr int NN = 50000;   // nodes
constexpr int NE = 800000;  // edges
constexpr int IC = 64;      // in channels
constexpr int OC = 128;     // out channels
constexpr int NH = 4;       // heads
constexpr unsigned F32_ONE = 0x3F800000u;
// 1/sqrt(32) * log2(e): exp(l) = exp2(l*log2e), constants fused
constexpr float KC = 0.25503486f;

__device__ __forceinline__ float ldf(const void* p, int i, bool f32) {
    return f32 ? ((const float*)p)[i]
               : __bfloat162float(((const bf16*)p)[i]);
}

__device__ __forceinline__ int ld_idx(const void* p, long long i, bool i64) {
    return i64 ? (int)((const long long*)p)[i] : ((const int*)p)[i];
}

// inline edge-index width probe: int64 node indices (<2^31) have zero high words
__device__ __forceinline__ bool probe_i64(const void* ei) {
    const unsigned* u = (const unsigned*)ei;
    return (u[1] | u[3] | u[5] | u[7]) == 0u;
}

// f32 -> bf16 bits (RNE)
__device__ __forceinline__ unsigned f2bu(float x) {
    unsigned u = __float_as_uint(x);
    return (u + 0x7FFFu + ((u >> 16) & 1u)) >> 16;
}

// ---- fp8 e4m3 helpers (HW path with manual fallback) ----------------------
__device__ __forceinline__ unsigned char f32_to_fp8(float x) {
#if __has_builtin(__builtin_amdgcn_cvt_pk_fp8_f32)
    return (unsigned char)(__builtin_amdgcn_cvt_pk_fp8_f32(x, x, 0, false) & 0xFF);
#else
    unsigned bits = __float_as_uint(x);
    unsigned s = bits >> 31;
    float a = fabsf(x);
    if (a >= 448.f) return (unsigned char)((s << 7) | 0x7E);
    if (a < 0.015625f) {
        int m = (int)(a * 512.f + 0.5f);
        if (m >= 8) return (unsigned char)((s << 7) | 0x08);
        return (unsigned char)((s << 7) | m);
    }
    unsigned ab = (bits & 0x7FFFFFFFu) + 0x00080000u;
    int e8 = (int)(ab >> 23) - 127 + 7;
    unsigned m3 = (ab >> 20) & 7u;
    if (e8 >= 16) return (unsigned char)((s << 7) | 0x7E);
    return (unsigned char)((s << 7) | ((unsigned)e8 << 3) | m3);
#endif
}

__device__ __forceinline__ void fp8x4_to_f32(unsigned u, float& f0, float& f1,
                                             float& f2, float& f3) {
#if __has_builtin(__builtin_amdgcn_cvt_pk_f32_fp8)
    f32x2 lo = __builtin_amdgcn_cvt_pk_f32_fp8(u, false);
    f32x2 hi = __builtin_amdgcn_cvt_pk_f32_fp8(u, true);
    f0 = lo[0]; f1 = lo[1]; f2 = hi[0]; f3 = hi[1];
#else
    float r[4];
#pragma unroll
    for (int j = 0; j < 4; ++j) {
        unsigned b = (u >> (8 * j)) & 0xFF;
        unsigned s = b >> 7, e = (b >> 3) & 15, m = b & 7;
        float v = (e == 0) ? (float)m * 0.001953125f
                           : __uint_as_float(((e + 120u) << 23) | (m << 20));
        r[j] = s ? -v : v;
    }
    f0 = r[0]; f1 = r[1]; f2 = r[2]; f3 = r[3];
#endif
}

__device__ __forceinline__ void fp8x2_to_f32(unsigned u, float& f0, float& f1) {
#if __has_builtin(__builtin_amdgcn_cvt_pk_f32_fp8)
    f32x2 lo = __builtin_amdgcn_cvt_pk_f32_fp8(u, false);
    f0 = lo[0]; f1 = lo[1];
#else
    float r[2];
#pragma unroll
    for (int j = 0; j < 2; ++j) {
        unsigned b = (u >> (8 * j)) & 0xFF;
        unsigned s = b >> 7, e = (b >> 3) & 15, m = b & 7;
        float v = (e == 0) ? (float)m * 0.001953125f
                           : __uint_as_float(((e + 120u) << 23) | (m << 20));
        r[j] = s ? -v : v;
    }
    f0 = r[0]; f1 = r[1];
#endif
}

// ---------------------------------------------------------------------------
// prep: fused one-shot conversions + csr_count. (cnt/ssum zeroed by memset)
// ---------------------------------------------------------------------------
constexpr int PB_X   = 12500;
constexpr int PB_W   = 160;
constexpr int PB_WO  = 64;
constexpr int PB_CNT = 3125;   // csr_count: NE/256

__global__ __launch_bounds__(256) void prep(
    const void* __restrict__ x,
    const void* __restrict__ Wq, const void* __restrict__ bq,
    const void* __restrict__ Wk, const void* __restrict__ bk,
    const void* __restrict__ Wv, const void* __restrict__ bv,
    const void* __restrict__ We1, const void* __restrict__ be1,
    const void* __restrict__ We2, const void* __restrict__ be2,
    const void* __restrict__ Wo,  const unsigned* __restrict__ gw,
    const void* __restrict__ eia, const void* __restrict__ eib, int split,
    bf16* __restrict__ xb, bf16* __restrict__ WcatT, bf16* __restrict__ WoT,
    int* __restrict__ cnt,
    float* __restrict__ be1f, float* __restrict__ We2f, float* __restrict__ be2f,
    float* __restrict__ bcat)
{
    const bool f32 = (gw[0] == F32_ONE);
    int b = blockIdx.x, t = threadIdx.x;
    if (b < PB_X) {
        int i = b * 256 + t;
        if (i < NN * IC) xb[i] = __float2bfloat16(ldf(x, i, f32));
    } else if (b < PB_X + PB_W) {
        int idx = (b - PB_X) * 256 + t;         // n*64 + k
        int n = idx >> 6, k = idx & 63;
        int sel = n >> 7, c = n & 127;
        float v;
        if (sel == 0)      v = ldf(Wq, k * OC + c, f32);
        else if (sel == 1) v = ldf(Wk, k * OC + c, f32);
        else if (sel == 2) v = ldf(Wv, k * OC + c, f32);
        else if (sel == 3) v = ldf(We1, k * OC + c, f32);
        else               v = ldf(We1, (IC + k) * OC + c, f32);
        WcatT[idx] = __float2bfloat16(v);
    } else if (b < PB_X + PB_W + PB_WO) {
        int idx = (b - PB_X - PB_W) * 256 + t;  // n*128 + k
        int n = idx >> 7, k = idx & 127;
        WoT[idx] = __float2bfloat16(ldf(Wo, k * OC + n, f32));
    } else if (b < PB_X + PB_W + PB_WO + PB_CNT) {
        const bool i64 = probe_i64(eia);
        long long e = (long long)(b - PB_X - PB_W - PB_WO) * 256 + t;
        int d = split ? ld_idx(eib, e, i64) : ld_idx(eia, NE + e, i64);
        atomicAdd(&cnt[d], 1);
    } else {
        if (t < OC) be1f[t] = ldf(be1, t, f32);
        for (int i = t; i < OC * NH; i += 256) We2f[i] = ldf(We2, i, f32);
        if (t < NH) be2f[t] = ldf(be2, t, f32);
        for (int n = t; n < 5 * OC; n += 256) {
            int sel = n >> 7, c = n & 127;
            float bb = 0.f;
            if (sel == 0) bb = ldf(bq, c, f32);
            else if (sel == 1) bb = ldf(bk, c, f32);
            else if (sel == 2) bb = ldf(bv, c, f32);
            bcat[n] = bb;
        }
    }
}

// ---------------------------------------------------------------------------
// csr_scan: exclusive prefix over cnt -> rowptr, cursor
// ---------------------------------------------------------------------------
__global__ __launch_bounds__(1024) void csr_scan(const int* __restrict__ cnt,
                                                 int* __restrict__ rowptr,
                                                 int* __restrict__ cursor)
{
    constexpr int T = 1024;
    constexpr int PER = (NN + T - 1) / T;
    __shared__ int psum[T];
    int t = threadIdx.x;
    int base = t * PER;
    int local = 0;
    for (int j = 0; j < PER; ++j) {
        int idx = base + j;
        if (idx < NN) local += cnt[idx];
    }
    psum[t] = local;
    __syncthreads();
    for (int off = 1; off < T; off <<= 1) {
        int v = (t >= off) ? psum[t - off] : 0;
        __syncthreads();
        psum[t] += v;
        __syncthreads();
    }
    int run = (t == 0) ? 0 : psum[t - 1];
    for (int j = 0; j < PER; ++j) {
        int idx = base + j;
        if (idx < NN) {
            rowptr[idx] = run;
            cursor[idx] = run;
            run += cnt[idx];
        }
    }
    if (t == T - 1) rowptr[NN] = run;
}

// ---------------------------------------------------------------------------
// node_gemm (+fused csr_fill): blocks [0,3125) GEMM, [3125,6250) fill.
// GEMM: D[50000 x 640] = xb @ Wcat + bcat (MFMA), fp8 packed outputs.
// ---------------------------------------------------------------------------
constexpr int NG_GEMM = 3125;   // NN/16
constexpr int NG_FILL = 3125;   // NE/256

__global__ __launch_bounds__(256) void node_gemm(
    const bf16* __restrict__ xb, const bf16* __restrict__ WcatT,
    const float* __restrict__ bcat,
    unsigned char* __restrict__ qb_dst, unsigned char* __restrict__ ka_src,
    unsigned char* __restrict__ vf8,
    const void* __restrict__ eia, const void* __restrict__ eib, int split,
    int* __restrict__ cursor, int* __restrict__ ssrc)
{
    if (blockIdx.x >= NG_GEMM) {
        // ---- csr_fill ----
        const bool i64 = probe_i64(eia);
        long long e = (long long)(blockIdx.x - NG_GEMM) * 256 + threadIdx.x;
        int s = ld_idx(eia, e, i64);
        int d = split ? ld_idx(eib, e, i64) : ld_idx(eia, NE + e, i64);
        int pos = atomicAdd(&cursor[d], 1);
        ssrc[pos] = s;
        return;
    }
    int wave = threadIdx.x >> 6;
    int lane = threadIdx.x & 63;
    int quad = lane >> 4;
    int l16  = lane & 15;
    int row_base = blockIdx.x * 16;
    int m = row_base + l16;

    short8 a0 = *(const short8*)(xb + (size_t)m * IC + quad * 8);
    short8 a1 = *(const short8*)(xb + (size_t)m * IC + 32 + quad * 8);

#pragma unroll
    for (int t = 0; t < 10; ++t) {
        int colbase = wave * 160 + t * 16;
        const bf16* bp = WcatT + (size_t)(colbase + l16) * IC + quad * 8;
        short8 b0 = *(const short8*)(bp);
        short8 b1 = *(const short8*)(bp + 32);
        f32x4 acc = {0.f, 0.f, 0.f, 0.f};
        acc = __builtin_amdgcn_mfma_f32_16x16x32_bf16(a0, b0, acc, 0, 0, 0);
        acc = __builtin_amdgcn_mfma_f32_16x16x32_bf16(a1, b1, acc, 0, 0, 0);

        float bias = bcat[colbase + l16];
        int sel = colbase >> 7;
        int cc  = (colbase & 127) + l16;
#pragma unroll
        for (int r = 0; r < 4; ++r) {
            int node = row_base + quad * 4 + r;
            unsigned char val = f32_to_fp8(acc[r] + bias);
            if (sel == 0)      qb_dst[(size_t)node * 256 + cc] = val;
            else if (sel == 1) ka_src[(size_t)node * 256 + cc] = val;
            else if (sel == 2) vf8[(size_t)node * OC + cc] = val;
            else if (sel == 3) ka_src[(size_t)node * 256 + 128 + cc] = val;
            else               qb_dst[(size_t)node * 256 + 128 + cc] = val;
        }
    }
}

// ---------------------------------------------------------------------------
// edge_gather: FUSED edge logit + softmax-weighted aggregation, 2-edge ILP.
// One wave per dst node; coef=exp(logit) unnormalized; agg + s partials.
// ---------------------------------------------------------------------------
__global__ __launch_bounds__(256) void edge_gather(
    const int* __restrict__ rowptr, const int* __restrict__ ssrc,
    const unsigned char* __restrict__ qb_dst, const unsigned char* __restrict__ ka_src,
    const unsigned char* __restrict__ vf8,
    const float* __restrict__ be1f, const float* __restrict__ We2f,
    const float* __restrict__ be2f,
    bf16* __restrict__ aggb, float* __restrict__ spart)
{
    int node = blockIdx.x * 4 + (threadIdx.x >> 6);
    int lane = threadIdx.x & 63;
    int li   = lane & 31;
    int c    = li << 2;
    int j    = li & 3;
    int myh  = lane >> 4;

    // dst row once: lane<32 -> q chunk, lane>=32 -> b chunk
    unsigned drow = *(const unsigned*)(qb_dst + (size_t)node * 256 + lane * 4);
    float d0, d1, d2, d3;
    fp8x4_to_f32(drow, d0, d1, d2, d3);

    float4 vb1 = *(const float4*)(be1f + c);
    float4 w0 = *(const float4*)(We2f + 4 * c);
    float4 w1 = *(const float4*)(We2f + 4 * (c + 1));
    float4 w2 = *(const float4*)(We2f + 4 * (c + 2));
    float4 w3 = *(const float4*)(We2f + 4 * (c + 3));
    float be2h = be2f[myh];

    int beg = rowptr[node], end = rowptr[node + 1];
    float o0 = 0.f, o1 = 0.f, s_acc = 0.f;

    if (beg < end) {
        int ia = beg, ib = (beg + 1 < end) ? beg + 1 : end - 1;
        int sa = ssrc[ia], sb = ssrc[ib];
        unsigned srowA = *(const unsigned*)(ka_src + (size_t)sa * 256 + lane * 4);
        unsigned uvA   = *(const unsigned short*)(vf8 + (size_t)sa * OC + 2 * lane);
        unsigned srowB = *(const unsigned*)(ka_src + (size_t)sb * 256 + lane * 4);
        unsigned uvB   = *(const unsigned short*)(vf8 + (size_t)sb * OC + 2 * lane);

        for (int p = beg; p < end; p += 2) {
            bool hasB = (p + 1 < end);
            // clamped prefetch of next pair
            int na = (p + 2 < end) ? p + 2 : end - 1;
            int nb = (p + 3 < end) ? p + 3 : end - 1;
            int sna = ssrc[na], snb = ssrc[nb];
            unsigned srowC = *(const unsigned*)(ka_src + (size_t)sna * 256 + lane * 4);
            unsigned uvC   = *(const unsigned short*)(vf8 + (size_t)sna * OC + 2 * lane);
            unsigned srowD = *(const unsigned*)(ka_src + (size_t)snb * 256 + lane * 4);
            unsigned uvD   = *(const unsigned short*)(vf8 + (size_t)snb * OC + 2 * lane);

            // decode both src rows
            float sA0, sA1, sA2, sA3, sB0, sB1, sB2, sB3;
            fp8x4_to_f32(srowA, sA0, sA1, sA2, sA3);
            fp8x4_to_f32(srowB, sB0, sB1, sB2, sB3);

            // dual dot (valid on lower half: d=q, s=k)
            float tA = d0 * sA0 + d1 * sA1 + d2 * sA2 + d3 * sA3;
            float tB = d0 * sB0 + d1 * sB1 + d2 * sB2 + d3 * sB3;
            tA += __shfl_xor(tA, 1);  tB += __shfl_xor(tB, 1);
            tA += __shfl_xor(tA, 2);  tB += __shfl_xor(tB, 2);
            tA += __shfl_xor(tA, 4);  tB += __shfl_xor(tB, 4);

            // dual gate (valid on upper half: d=b, s=a)
            float hA0 = fmaxf(sA0 + d0 + vb1.x, 0.f);
            float hA1 = fmaxf(sA1 + d1 + vb1.y, 0.f);
            float hA2 = fmaxf(sA2 + d2 + vb1.z, 0.f);
            float hA3 = fmaxf(sA3 + d3 + vb1.w, 0.f);
            float hB0 = fmaxf(sB0 + d0 + vb1.x, 0.f);
            float hB1 = fmaxf(sB1 + d1 + vb1.y, 0.f);
            float hB2 = fmaxf(sB2 + d2 + vb1.z, 0.f);
            float hB3 = fmaxf(sB3 + d3 + vb1.w, 0.f);
            float pA0 = hA0 * w0.x + hA1 * w1.x + hA2 * w2.x + hA3 * w3.x;
            float pA1 = hA0 * w0.y + hA1 * w1.y + hA2 * w2.y + hA3 * w3.y;
            float pA2 = hA0 * w0.z + hA1 * w1.z + hA2 * w2.z + hA3 * w3.z;
            float pA3 = hA0 * w0.w + hA1 * w1.w + hA2 * w2.w + hA3 * w3.w;
            float pB0 = hB0 * w0.x + hB1 * w1.x + hB2 * w2.x + hB3 * w3.x;
            float pB1 = hB0 * w0.y + hB1 * w1.y + hB2 * w2.y + hB3 * w3.y;
            float pB2 = hB0 * w0.z + hB1 * w1.z + hB2 * w2.z + hB3 * w3.z;
            float pB3 = hB0 * w0.w + hB1 * w1.w + hB2 * w2.w + hB3 * w3.w;
            pA0 += __shfl_xor(pA0, 1); pB0 += __shfl_xor(pB0, 1);
            pA1 += __shfl_xor(pA1, 1); pB1 += __shfl_xor(pB1, 1);
            pA2 += __shfl_xor(pA2, 1); pB2 += __shfl_xor(pB2, 1);
            pA3 += __shfl_xor(pA3, 1); pB3 += __shfl_xor(pB3, 1);
            pA0 += __shfl_xor(pA0, 2); pB0 += __shfl_xor(pB0, 2);
            pA1 += __shfl_xor(pA1, 2); pB1 += __shfl_xor(pB1, 2);
            pA2 += __shfl_xor(pA2, 2); pB2 += __shfl_xor(pB2, 2);
            pA3 += __shfl_xor(pA3, 2); pB3 += __shfl_xor(pB3, 2);
            float pjA = (j == 0) ? pA0 : (j == 1) ? pA1 : (j == 2) ? pA2 : pA3;
            float pjB = (j == 0) ? pB0 : (j == 1) ? pB1 : (j == 2) ? pB2 : pB3;
            pjA += __shfl_xor(pjA, 4);  pjB += __shfl_xor(pjB, 4);
            pjA += __shfl_xor(pjA, 8);  pjB += __shfl_xor(pjB, 8);
            pjA += __shfl_xor(pjA, 16); pjB += __shfl_xor(pjB, 16);

            float tjA  = __shfl(tA, 8 * myh);
            float tjB  = __shfl(tB, 8 * myh);
            float pjhA = __shfl(pjA, 32 + myh);
            float pjhB = __shfl(pjB, 32 + myh);
            float coefA = exp2f(tjA * (pjhA + be2h) * KC);
            float coefB = hasB ? exp2f(tjB * (pjhB + be2h) * KC) : 0.f;
            s_acc += coefA + coefB;

            float vA0, vA1, vB0, vB1;
            fp8x2_to_f32(uvA, vA0, vA1);
            fp8x2_to_f32(uvB, vB0, vB1);
            o0 = fmaf(coefA, vA0, fmaf(coefB, vB0, o0));
            o1 = fmaf(coefA, vA1, fmaf(coefB, vB1, o1));

            srowA = srowC; uvA = uvC; srowB = srowD; uvB = uvD;
        }
    }
    *(unsigned*)(aggb + (size_t)node * OC + 2 * lane) = f2bu(o0) | (f2bu(o1) << 16);
    if ((lane & 15) == 0) spart[node * 4 + myh] = s_acc;
}

// ---------------------------------------------------------------------------
// s_reduce: PARALLEL reduction of spart (NN*4) -> ssum[4] via atomics.
// ---------------------------------------------------------------------------
constexpr int SR_BLOCKS = 98;
__global__ __launch_bounds__(256) void s_reduce(const float* __restrict__ spart,
                                                float* __restrict__ ssum)
{
    int tid = blockIdx.x * 256 + threadIdx.x;
    int h = threadIdx.x & 3;                 // fixed per thread
    float s = 0.f;
    for (int i = tid; i < NN * 4; i += SR_BLOCKS * 256) s += spart[i];
#pragma unroll
    for (int off = 4; off <= 32; off <<= 1) s += __shfl_xor(s, off);
    __shared__ float sm[4][4];               // [wave][h]
    int lane = threadIdx.x & 63, w = threadIdx.x >> 6;
    if (lane < 4) sm[w][h] = s;
    __syncthreads();
    if (threadIdx.x < 4) {
        float tot = sm[0][h] + sm[1][h] + sm[2][h] + sm[3][h];
        atomicAdd(&ssum[h], tot);
    }
}

// ---------------------------------------------------------------------------
// out_gemm: MFMA out GEMM + fused softmax-normalization + fused LN.
// A-fragments (bf16, unnormalized agg) scaled by 1/ssum[head] on load —
// each short8 fragment spans exactly one head (32 channels/head).
// ---------------------------------------------------------------------------
__global__ __launch_bounds__(256) void out_gemm(
    const bf16* __restrict__ aggb, const bf16* __restrict__ WoT,
    const void* __restrict__ bo, const void* __restrict__ gamma,
    const void* __restrict__ beta, const unsigned* __restrict__ gw,
    const float* __restrict__ ssum,
    void* __restrict__ out)
{
    const bool f32 = (gw[0] == F32_ONE);
    int wave = threadIdx.x >> 6;
    int lane = threadIdx.x & 63;
    int quad = lane >> 4;
    int l16  = lane & 15;
    int rb = blockIdx.x * 64 + wave * 16;
    int m = rb + l16;
    int ma = (m < NN) ? m : 0;

    short8 a[4];
#pragma unroll
    for (int h = 0; h < 4; ++h) {
        short8 raw = *(const short8*)(aggb + (size_t)ma * OC + h * 32 + quad * 8);
        float invh = 1.0f / ssum[h];
#pragma unroll
        for (int jj = 0; jj < 8; ++jj) {
            float f = __uint_as_float(((unsigned)(unsigned short)raw[jj]) << 16) * invh;
            raw[jj] = (short)f2bu(f);
        }
        a[h] = raw;
    }

    float o[8][4];
#pragma unroll
    for (int t = 0; t < 8; ++t) {
        const bf16* bp = WoT + (size_t)(t * 16 + l16) * OC + quad * 8;
        f32x4 acc = {0.f, 0.f, 0.f, 0.f};
#pragma unroll
        for (int h = 0; h < 4; ++h) {
            short8 bfr = *(const short8*)(bp + h * 32);
            acc = __builtin_amdgcn_mfma_f32_16x16x32_bf16(a[h], bfr, acc, 0, 0, 0);
        }
        float bias = ldf(bo, t * 16 + l16, f32);
#pragma unroll
        for (int r = 0; r < 4; ++r) o[t][r] = acc[r] + bias;
    }

#pragma unroll
    for (int r = 0; r < 4; ++r) {
        float s1 = 0.f, s2 = 0.f;
#pragma unroll
        for (int t = 0; t < 8; ++t) { s1 += o[t][r]; s2 += o[t][r] * o[t][r]; }
#pragma unroll
        for (int off = 1; off <= 8; off <<= 1) {
            s1 += __shfl_xor(s1, off);
            s2 += __shfl_xor(s2, off);
        }
        float mu = s1 * (1.0f / OC);
        float var = fmaxf(s2 * (1.0f / OC) - mu * mu, 0.f);
        float rs = rsqrtf(var + 1e-5f);
        int node = rb + quad * 4 + r;
        if (node < NN) {
#pragma unroll
            for (int t = 0; t < 8; ++t) {
                int col = t * 16 + l16;
                float y = (o[t][r] - mu) * rs * ldf(gamma, col, f32) + ldf(beta, col, f32);
                if (f32) ((float*)out)[(size_t)node * OC + col] = y;
                else     ((bf16*)out)[(size_t)node * OC + col] = __float2bfloat16(y);
            }
        }
    }
}

// ---------------------------------------------------------------------------
extern "C" void kernel_launch(void* const* d_in, const int* in_sizes, int n_in,
                              void* d_out, int out_size, void* d_ws, size_t ws_size,
                              hipStream_t stream)
{
    int p = 0;
    const void* x   = d_in[p++];
    const void* eia = d_in[p++];
    const void* eib = eia;
    int split = 0;
    if (n_in >= 17) { eib = d_in[p++]; split = 1; }
    const void* Wq   = d_in[p++];
    const void* bq   = d_in[p++];
    const void* Wk   = d_in[p++];
    const void* bk   = d_in[p++];
    const void* Wv   = d_in[p++];
    const void* bv   = d_in[p++];
    const void* We1  = d_in[p++];
    const void* be1  = d_in[p++];
    const void* We2  = d_in[p++];
    const void* be2  = d_in[p++];
    const void* Wo   = d_in[p++];
    const void* bo   = d_in[p++];
    const void* gamma= d_in[p++];
    const void* beta = d_in[p++];
    const unsigned* gw = (const unsigned*)gamma;

    // workspace layout (~44 MB). cnt and ssum adjacent -> single memset.
    char* w = (char*)d_ws;
    bf16*  xb     = (bf16*)w;                  w += (size_t)NN * IC * 2;  // 6.4 MB
    unsigned char* qb_dst = (unsigned char*)w; w += (size_t)NN * 256;     // 12.8 MB
    unsigned char* ka_src = (unsigned char*)w; w += (size_t)NN * 256;     // 12.8 MB
    unsigned char* vf8    = (unsigned char*)w; w += (size_t)NN * OC;      // 6.4 MB
    int*   ssrc   = (int*)w;                   w += (size_t)NE * 4;       // 3.2 MB
    int*   cnt    = (int*)w;                   w += (size_t)NN * 4;       // 200 KB
    float* ssum   = (float*)w;                 w += 8 * 4;                // 32 B (memset w/ cnt)
    int*   rowptr = (int*)w;                   w += (size_t)(NN + 1) * 4;
    int*   cursor = (int*)w;                   w += (size_t)NN * 4;
    float* spart  = (float*)w;                 w += (size_t)NN * 4 * 4;   // 800 KB
    float* be1f   = (float*)w;                 w += OC * 4;
    float* We2f   = (float*)w;                 w += OC * NH * 4;
    float* be2f   = (float*)w;                 w += NH * 4;
    bf16*  WcatT  = (bf16*)w;                  w += (size_t)5 * OC * IC * 2;
    float* bcat   = (float*)w;                 w += 5 * OC * 4;
    bf16*  WoT    = (bf16*)w;                  w += (size_t)OC * OC * 2;

    // alias: aggb over qb_dst (row n read only by wave n before its write)
    bf16*  aggb   = (bf16*)qb_dst;

    if (ws_size < (size_t)((char*)w - (char*)d_ws)) return;

    hipMemsetAsync(cnt, 0, (size_t)NN * 4 + 32, stream);   // cnt + ssum
    prep<<<PB_X + PB_W + PB_WO + PB_CNT + 1, 256, 0, stream>>>(
        x, Wq, bq, Wk, bk, Wv, bv, We1, be1, We2, be2, Wo, gw,
        eia, eib, split,
        xb, WcatT, WoT, cnt, be1f, We2f, be2f, bcat);
    csr_scan<<<1, 1024, 0, stream>>>(cnt, rowptr, cursor);
    node_gemm<<<NG_GEMM + NG_FILL, 256, 0, stream>>>(
        xb, WcatT, bcat, qb_dst, ka_src, vf8, eia, eib, split, cursor, ssrc);
    edge_gather<<<NN / 4, 256, 0, stream>>>(rowptr, ssrc, qb_dst, ka_src, vf8,
                                            be1f, We2f, be2f, aggb, spart);
    s_reduce<<<SR_BLOCKS, 256, 0, stream>>>(spart, ssum);
    out_gemm<<<(NN + 63) / 64, 256, 0, stream>>>(aggb, WoT, bo, gamma, beta, gw,
                                                 ssum, d_out);
}

// Round 14
// 520.293 us; speedup vs baseline: 1.3934x; 1.0005x over previous
//
#include <hip/hip_runtime.h>
#include <hip/hip_bf16.h>

typedef __hip_bfloat16 bf16;
typedef __attribute__((ext_vector_type(8))) short short8;   // 8 bf16 (4 VGPRs)
typedef __attribute__((ext_vector_type(4))) float f32x4;    // 4 fp32 acc
typedef __attribute__((ext_vector_type(2))) float f32x2;
typedef _Float16 h2 __attribute__((ext_vector_type(2)));    // packed half2

constexpr int NN = 50000;   // nodes
constexpr int NE = 800000;  // edges
constexpr int IC = 64;      // in channels
constexpr int OC = 128;     // out channels
constexpr int NH = 4;       // heads
constexpr unsigned F32_ONE = 0x3F800000u;
// 1/sqrt(32) * log2(e): exp(l) = exp2(l*log2e), constants fused
constexpr float KC = 0.25503486f;

__device__ __forceinline__ float ldf(const void* p, int i, bool f32) {
    return f32 ? ((const float*)p)[i]
               : __bfloat162float(((const bf16*)p)[i]);
}

__device__ __forceinline__ int ld_idx(const void* p, long long i, bool i64) {
    return i64 ? (int)((const long long*)p)[i] : ((const int*)p)[i];
}

__device__ __forceinline__ bool probe_i64(const void* ei) {
    const unsigned* u = (const unsigned*)ei;
    return (u[1] | u[3] | u[5] | u[7]) == 0u;
}

// f32 -> bf16 bits (RNE)
__device__ __forceinline__ unsigned f2bu(float x) {
    unsigned u = __float_as_uint(x);
    return (u + 0x7FFFu + ((u >> 16) & 1u)) >> 16;
}

__device__ __forceinline__ h2 u2h(unsigned u) { return __builtin_bit_cast(h2, u); }

// dot2: c += a[0]*b[0] + a[1]*b[1] (f16 inputs, f32 accum)
__device__ __forceinline__ float fdot2(h2 a, h2 b, float c) {
#if __has_builtin(__builtin_amdgcn_fdot2)
    return __builtin_amdgcn_fdot2(a, b, c, false);
#else
    return c + (float)a[0] * (float)b[0] + (float)a[1] * (float)b[1];
#endif
}

__device__ __forceinline__ h2 relu2(h2 a) {
    h2 z = {(_Float16)0.f, (_Float16)0.f};
#if __has_builtin(__builtin_elementwise_max)
    return __builtin_elementwise_max(a, z);
#else
    h2 r;
    r[0] = a[0] > (_Float16)0.f ? a[0] : (_Float16)0.f;
    r[1] = a[1] > (_Float16)0.f ? a[1] : (_Float16)0.f;
    return r;
#endif
}

// ---- fp8 e4m3 helpers ------------------------------------------------------
__device__ __forceinline__ unsigned char f32_to_fp8(float x) {
#if __has_builtin(__builtin_amdgcn_cvt_pk_fp8_f32)
    return (unsigned char)(__builtin_amdgcn_cvt_pk_fp8_f32(x, x, 0, false) & 0xFF);
#else
    unsigned bits = __float_as_uint(x);
    unsigned s = bits >> 31;
    float a = fabsf(x);
    if (a >= 448.f) return (unsigned char)((s << 7) | 0x7E);
    if (a < 0.015625f) {
        int m = (int)(a * 512.f + 0.5f);
        if (m >= 8) return (unsigned char)((s << 7) | 0x08);
        return (unsigned char)((s << 7) | m);
    }
    unsigned ab = (bits & 0x7FFFFFFFu) + 0x00080000u;
    int e8 = (int)(ab >> 23) - 127 + 7;
    unsigned m3 = (ab >> 20) & 7u;
    if (e8 >= 16) return (unsigned char)((s << 7) | 0x7E);
    return (unsigned char)((s << 7) | ((unsigned)e8 << 3) | m3);
#endif
}

__device__ __forceinline__ void fp8x2_to_f32(unsigned u, float& f0, float& f1) {
#if __has_builtin(__builtin_amdgcn_cvt_pk_f32_fp8)
    f32x2 lo = __builtin_amdgcn_cvt_pk_f32_fp8(u, false);
    f0 = lo[0]; f1 = lo[1];
#else
    float r[2];
#pragma unroll
    for (int j = 0; j < 2; ++j) {
        unsigned b = (u >> (8 * j)) & 0xFF;
        unsigned s = b >> 7, e = (b >> 3) & 15, m = b & 7;
        float v = (e == 0) ? (float)m * 0.001953125f
                           : __uint_as_float(((e + 120u) << 23) | (m << 20));
        r[j] = s ? -v : v;
    }
    f0 = r[0]; f1 = r[1];
#endif
}

// ---------------------------------------------------------------------------
// prep: fused one-shot conversions + csr_count. (cnt/ssum zeroed by memset)
// bcat: [0,128)=bq, [128,256)=bk, [256,384)=bv, [384,512)=0 (a), [512,640)=be1 (b')
// ---------------------------------------------------------------------------
constexpr int PB_X   = 12500;
constexpr int PB_W   = 160;
constexpr int PB_WO  = 64;
constexpr int PB_CNT = 3125;   // csr_count: NE/256

__global__ __launch_bounds__(256) void prep(
    const void* __restrict__ x,
    const void* __restrict__ Wq, const void* __restrict__ bq,
    const void* __restrict__ Wk, const void* __restrict__ bk,
    const void* __restrict__ Wv, const void* __restrict__ bv,
    const void* __restrict__ We1, const void* __restrict__ be1,
    const void* __restrict__ We2, const void* __restrict__ be2,
    const void* __restrict__ Wo,  const unsigned* __restrict__ gw,
    const void* __restrict__ eia, const void* __restrict__ eib, int split,
    bf16* __restrict__ xb, bf16* __restrict__ WcatT, bf16* __restrict__ WoT,
    int* __restrict__ cnt,
    unsigned* __restrict__ We2h, float* __restrict__ be2f,
    float* __restrict__ bcat)
{
    const bool f32 = (gw[0] == F32_ONE);
    int b = blockIdx.x, t = threadIdx.x;
    if (b < PB_X) {
        int i = b * 256 + t;
        if (i < NN * IC) xb[i] = __float2bfloat16(ldf(x, i, f32));
    } else if (b < PB_X + PB_W) {
        int idx = (b - PB_X) * 256 + t;         // n*64 + k
        int n = idx >> 6, k = idx & 63;
        int sel = n >> 7, c = n & 127;
        float v;
        if (sel == 0)      v = ldf(Wq, k * OC + c, f32);
        else if (sel == 1) v = ldf(Wk, k * OC + c, f32);
        else if (sel == 2) v = ldf(Wv, k * OC + c, f32);
        else if (sel == 3) v = ldf(We1, k * OC + c, f32);
        else               v = ldf(We1, (IC + k) * OC + c, f32);
        WcatT[idx] = __float2bfloat16(v);
    } else if (b < PB_X + PB_W + PB_WO) {
        int idx = (b - PB_X - PB_W) * 256 + t;  // n*128 + k
        int n = idx >> 7, k = idx & 127;
        WoT[idx] = __float2bfloat16(ldf(Wo, k * OC + n, f32));
    } else if (b < PB_X + PB_W + PB_WO + PB_CNT) {
        const bool i64 = probe_i64(eia);
        long long e = (long long)(b - PB_X - PB_W - PB_WO) * 256 + t;
        int d = split ? ld_idx(eib, e, i64) : ld_idx(eia, NE + e, i64);
        atomicAdd(&cnt[d], 1);
    } else {
        if (t < NH) be2f[t] = ldf(be2, t, f32);
        // We2h: 64 channel-pairs x 4 heads, packed half2 each
        {
            int pp = t >> 2, j = t & 3;   // t in [0,256)
            h2 hv;
            hv[0] = (_Float16)ldf(We2, (2 * pp) * NH + j, f32);
            hv[1] = (_Float16)ldf(We2, (2 * pp + 1) * NH + j, f32);
            We2h[t] = __builtin_bit_cast(unsigned, hv);
        }
        for (int n = t; n < 5 * OC; n += 256) {
            int sel = n >> 7, c = n & 127;
            float bb = 0.f;
            if (sel == 0) bb = ldf(bq, c, f32);
            else if (sel == 1) bb = ldf(bk, c, f32);
            else if (sel == 2) bb = ldf(bv, c, f32);
            else if (sel == 4) bb = ldf(be1, c, f32);  // fold be1 into b'
            bcat[n] = bb;
        }
    }
}

// ---------------------------------------------------------------------------
// csr_scan: exclusive prefix over cnt -> rowptr, cursor
// ---------------------------------------------------------------------------
__global__ __launch_bounds__(1024) void csr_scan(const int* __restrict__ cnt,
                                                 int* __restrict__ rowptr,
                                                 int* __restrict__ cursor)
{
    constexpr int T = 1024;
    constexpr int PER = (NN + T - 1) / T;
    __shared__ int psum[T];
    int t = threadIdx.x;
    int base = t * PER;
    int local = 0;
    for (int j = 0; j < PER; ++j) {
        int idx = base + j;
        if (idx < NN) local += cnt[idx];
    }
    psum[t] = local;
    __syncthreads();
    for (int off = 1; off < T; off <<= 1) {
        int v = (t >= off) ? psum[t - off] : 0;
        __syncthreads();
        psum[t] += v;
        __syncthreads();
    }
    int run = (t == 0) ? 0 : psum[t - 1];
    for (int j = 0; j < PER; ++j) {
        int idx = base + j;
        if (idx < NN) {
            rowptr[idx] = run;
            cursor[idx] = run;
            run += cnt[idx];
        }
    }
    if (t == T - 1) rowptr[NN] = run;
}

// ---------------------------------------------------------------------------
// node_gemm (+fused csr_fill): blocks [0,3125) GEMM, [3125,6250) fill.
// GEMM: D[50000 x 640] = xb @ Wcat + bcat (MFMA).
// Outputs: qb_dst row (f16, 512B) = [q 128ch | b' 128ch];
//          ka_src row (f16, 512B) = [k 128ch | a 128ch]; vf8 row 128B (fp8).
// ---------------------------------------------------------------------------
constexpr int NG_GEMM = 3125;   // NN/16
constexpr int NG_FILL = 3125;   // NE/256

__global__ __launch_bounds__(256) void node_gemm(
    const bf16* __restrict__ xb, const bf16* __restrict__ WcatT,
    const float* __restrict__ bcat,
    unsigned char* __restrict__ qb_dst, unsigned char* __restrict__ ka_src,
    unsigned char* __restrict__ vf8,
    const void* __restrict__ eia, const void* __restrict__ eib, int split,
    int* __restrict__ cursor, int* __restrict__ ssrc)
{
    if (blockIdx.x >= NG_GEMM) {
        // ---- csr_fill ----
        const bool i64 = probe_i64(eia);
        long long e = (long long)(blockIdx.x - NG_GEMM) * 256 + threadIdx.x;
        int s = ld_idx(eia, e, i64);
        int d = split ? ld_idx(eib, e, i64) : ld_idx(eia, NE + e, i64);
        int pos = atomicAdd(&cursor[d], 1);
        ssrc[pos] = s;
        return;
    }
    int wave = threadIdx.x >> 6;
    int lane = threadIdx.x & 63;
    int quad = lane >> 4;
    int l16  = lane & 15;
    int row_base = blockIdx.x * 16;
    int m = row_base + l16;

    short8 a0 = *(const short8*)(xb + (size_t)m * IC + quad * 8);
    short8 a1 = *(const short8*)(xb + (size_t)m * IC + 32 + quad * 8);

    _Float16* qh = (_Float16*)qb_dst;
    _Float16* kh = (_Float16*)ka_src;

#pragma unroll
    for (int t = 0; t < 10; ++t) {
        int colbase = wave * 160 + t * 16;
        const bf16* bp = WcatT + (size_t)(colbase + l16) * IC + quad * 8;
        short8 b0 = *(const short8*)(bp);
        short8 b1 = *(const short8*)(bp + 32);
        f32x4 acc = {0.f, 0.f, 0.f, 0.f};
        acc = __builtin_amdgcn_mfma_f32_16x16x32_bf16(a0, b0, acc, 0, 0, 0);
        acc = __builtin_amdgcn_mfma_f32_16x16x32_bf16(a1, b1, acc, 0, 0, 0);

        float bias = bcat[colbase + l16];
        int sel = colbase >> 7;
        int cc  = (colbase & 127) + l16;
#pragma unroll
        for (int r = 0; r < 4; ++r) {
            int node = row_base + quad * 4 + r;
            float fv = acc[r] + bias;
            if (sel == 2) {
                vf8[(size_t)node * OC + cc] = f32_to_fp8(fv);
            } else {
                _Float16 val = (_Float16)fv;
                if (sel == 0)      qh[(size_t)node * 256 + cc] = val;
                else if (sel == 1) kh[(size_t)node * 256 + cc] = val;
                else if (sel == 3) kh[(size_t)node * 256 + 128 + cc] = val;
                else               qh[(size_t)node * 256 + 128 + cc] = val;
            }
        }
    }
}

// ---------------------------------------------------------------------------
// edge_gather: FUSED edge logit + softmax-weighted aggregation, 2-edge ILP,
// packed-f16 math (dot2 / pk_add / pk_max), zero decode for q/k/a/b'.
// One wave per dst node. Agg row (bf16, 256B) written into the FIRST HALF of
// this node's qb_dst row (512B) — row n touched only by wave n, read first.
// ---------------------------------------------------------------------------
__global__ __launch_bounds__(256) void edge_gather(
    const int* __restrict__ rowptr, const int* __restrict__ ssrc,
    unsigned char* __restrict__ qb_dst, const unsigned char* __restrict__ ka_src,
    const unsigned char* __restrict__ vf8,
    const unsigned* __restrict__ We2h, const float* __restrict__ be2f,
    float* __restrict__ spart)
{
    int node = blockIdx.x * 4 + (threadIdx.x >> 6);
    int lane = threadIdx.x & 63;
    int li   = lane & 31;
    int j    = li & 3;
    int myh  = lane >> 4;

    // dst row once: lane<32 -> q chunk (4 ch), lane>=32 -> b' chunk
    uint2 du = *(const uint2*)(qb_dst + (size_t)node * 512 + lane * 8);
    h2 d0 = u2h(du.x), d1 = u2h(du.y);

    // gate weight half2 pairs for this lane's 4 channels
    uint4 wa = *(const uint4*)(We2h + li * 8);      // pair 2li,   j=0..3
    uint4 wb = *(const uint4*)(We2h + li * 8 + 4);  // pair 2li+1, j=0..3
    float be2h = be2f[myh];

    int beg = rowptr[node], end = rowptr[node + 1];
    float o0 = 0.f, o1 = 0.f, s_acc = 0.f;

    if (beg < end) {
        int ia = beg, ib = (beg + 1 < end) ? beg + 1 : end - 1;
        int sa = ssrc[ia], sb = ssrc[ib];
        uint2 srowA = *(const uint2*)(ka_src + (size_t)sa * 512 + lane * 8);
        unsigned uvA = *(const unsigned short*)(vf8 + (size_t)sa * OC + 2 * lane);
        uint2 srowB = *(const uint2*)(ka_src + (size_t)sb * 512 + lane * 8);
        unsigned uvB = *(const unsigned short*)(vf8 + (size_t)sb * OC + 2 * lane);

        for (int p = beg; p < end; p += 2) {
            bool hasB = (p + 1 < end);
            int na = (p + 2 < end) ? p + 2 : end - 1;
            int nb = (p + 3 < end) ? p + 3 : end - 1;
            int sna = ssrc[na], snb = ssrc[nb];
            uint2 srowC = *(const uint2*)(ka_src + (size_t)sna * 512 + lane * 8);
            unsigned uvC = *(const unsigned short*)(vf8 + (size_t)sna * OC + 2 * lane);
            uint2 srowD = *(const uint2*)(ka_src + (size_t)snb * 512 + lane * 8);
            unsigned uvD = *(const unsigned short*)(vf8 + (size_t)snb * OC + 2 * lane);

            h2 sA0 = u2h(srowA.x), sA1 = u2h(srowA.y);
            h2 sB0 = u2h(srowB.x), sB1 = u2h(srowB.y);

            // dual dot (valid on lower half: d=q, s=k)
            float tA = fdot2(d1, sA1, fdot2(d0, sA0, 0.f));
            float tB = fdot2(d1, sB1, fdot2(d0, sB0, 0.f));
            tA += __shfl_xor(tA, 1);  tB += __shfl_xor(tB, 1);
            tA += __shfl_xor(tA, 2);  tB += __shfl_xor(tB, 2);
            tA += __shfl_xor(tA, 4);  tB += __shfl_xor(tB, 4);

            // dual gate (valid on upper half: d=b'=b+be1, s=a)
            h2 hA0 = relu2(sA0 + d0), hA1 = relu2(sA1 + d1);
            h2 hB0 = relu2(sB0 + d0), hB1 = relu2(sB1 + d1);
            float pA0 = fdot2(hA1, u2h(wb.x), fdot2(hA0, u2h(wa.x), 0.f));
            float pA1 = fdot2(hA1, u2h(wb.y), fdot2(hA0, u2h(wa.y), 0.f));
            float pA2 = fdot2(hA1, u2h(wb.z), fdot2(hA0, u2h(wa.z), 0.f));
            float pA3 = fdot2(hA1, u2h(wb.w), fdot2(hA0, u2h(wa.w), 0.f));
            float pB0 = fdot2(hB1, u2h(wb.x), fdot2(hB0, u2h(wa.x), 0.f));
            float pB1 = fdot2(hB1, u2h(wb.y), fdot2(hB0, u2h(wa.y), 0.f));
            float pB2 = fdot2(hB1, u2h(wb.z), fdot2(hB0, u2h(wa.z), 0.f));
            float pB3 = fdot2(hB1, u2h(wb.w), fdot2(hB0, u2h(wa.w), 0.f));
            pA0 += __shfl_xor(pA0, 1); pB0 += __shfl_xor(pB0, 1);
            pA1 += __shfl_xor(pA1, 1); pB1 += __shfl_xor(pB1, 1);
            pA2 += __shfl_xor(pA2, 1); pB2 += __shfl_xor(pB2, 1);
            pA3 += __shfl_xor(pA3, 1); pB3 += __shfl_xor(pB3, 1);
            pA0 += __shfl_xor(pA0, 2); pB0 += __shfl_xor(pB0, 2);
            pA1 += __shfl_xor(pA1, 2); pB1 += __shfl_xor(pB1, 2);
            pA2 += __shfl_xor(pA2, 2); pB2 += __shfl_xor(pB2, 2);
            pA3 += __shfl_xor(pA3, 2); pB3 += __shfl_xor(pB3, 2);
            float pjA = (j == 0) ? pA0 : (j == 1) ? pA1 : (j == 2) ? pA2 : pA3;
            float pjB = (j == 0) ? pB0 : (j == 1) ? pB1 : (j == 2) ? pB2 : pB3;
            pjA += __shfl_xor(pjA, 4);  pjB += __shfl_xor(pjB, 4);
            pjA += __shfl_xor(pjA, 8);  pjB += __shfl_xor(pjB, 8);
            pjA += __shfl_xor(pjA, 16); pjB += __shfl_xor(pjB, 16);

            float tjA  = __shfl(tA, 8 * myh);
            float tjB  = __shfl(tB, 8 * myh);
            float pjhA = __shfl(pjA, 32 + myh);
            float pjhB = __shfl(pjB, 32 + myh);
            float coefA = exp2f(tjA * (pjhA + be2h) * KC);
            float coefB = hasB ? exp2f(tjB * (pjhB + be2h) * KC) : 0.f;
            s_acc += coefA + coefB;

            float vA0, vA1, vB0, vB1;
            fp8x2_to_f32(uvA, vA0, vA1);
            fp8x2_to_f32(uvB, vB0, vB1);
            o0 = fmaf(coefA, vA0, fmaf(coefB, vB0, o0));
            o1 = fmaf(coefA, vA1, fmaf(coefB, vB1, o1));

            srowA = srowC; uvA = uvC; srowB = srowD; uvB = uvD;
        }
    }
    // write agg row (bf16, 256B) into first half of this node's qb row
    *(unsigned*)(qb_dst + (size_t)node * 512 + lane * 4) = f2bu(o0) | (f2bu(o1) << 16);
    if ((lane & 15) == 0) spart[node * 4 + myh] = s_acc;
}

// ---------------------------------------------------------------------------
// s_reduce: PARALLEL reduction of spart (NN*4) -> ssum[4] via atomics.
// ---------------------------------------------------------------------------
constexpr int SR_BLOCKS = 98;
__global__ __launch_bounds__(256) void s_reduce(const float* __restrict__ spart,
                                                float* __restrict__ ssum)
{
    int tid = blockIdx.x * 256 + threadIdx.x;
    int h = threadIdx.x & 3;
    float s = 0.f;
    for (int i = tid; i < NN * 4; i += SR_BLOCKS * 256) s += spart[i];
#pragma unroll
    for (int off = 4; off <= 32; off <<= 1) s += __shfl_xor(s, off);
    __shared__ float sm[4][4];
    int lane = threadIdx.x & 63, w = threadIdx.x >> 6;
    if (lane < 4) sm[w][h] = s;
    __syncthreads();
    if (threadIdx.x < 4) {
        float tot = sm[0][h] + sm[1][h] + sm[2][h] + sm[3][h];
        atomicAdd(&ssum[h], tot);
    }
}

// ---------------------------------------------------------------------------
// out_gemm: MFMA out GEMM + fused softmax-normalization + fused LN.
// Agg rows live at stride 512 B inside qb_dst (first half of each row).
// ---------------------------------------------------------------------------
__global__ __launch_bounds__(256) void out_gemm(
    const unsigned char* __restrict__ aggv, const bf16* __restrict__ WoT,
    const void* __restrict__ bo, const void* __restrict__ gamma,
    const void* __restrict__ beta, const unsigned* __restrict__ gw,
    const float* __restrict__ ssum,
    void* __restrict__ out)
{
    const bool f32 = (gw[0] == F32_ONE);
    int wave = threadIdx.x >> 6;
    int lane = threadIdx.x & 63;
    int quad = lane >> 4;
    int l16  = lane & 15;
    int rb = blockIdx.x * 64 + wave * 16;
    int m = rb + l16;
    int ma = (m < NN) ? m : 0;

    const bf16* arow = (const bf16*)(aggv + (size_t)ma * 512);
    short8 a[4];
#pragma unroll
    for (int h = 0; h < 4; ++h) {
        short8 raw = *(const short8*)(arow + h * 32 + quad * 8);
        float invh = 1.0f / ssum[h];
#pragma unroll
        for (int jj = 0; jj < 8; ++jj) {
            float f = __uint_as_float(((unsigned)(unsigned short)raw[jj]) << 16) * invh;
            raw[jj] = (short)f2bu(f);
        }
        a[h] = raw;
    }

    float o[8][4];
#pragma unroll
    for (int t = 0; t < 8; ++t) {
        const bf16* bp = WoT + (size_t)(t * 16 + l16) * OC + quad * 8;
        f32x4 acc = {0.f, 0.f, 0.f, 0.f};
#pragma unroll
        for (int h = 0; h < 4; ++h) {
            short8 bfr = *(const short8*)(bp + h * 32);
            acc = __builtin_amdgcn_mfma_f32_16x16x32_bf16(a[h], bfr, acc, 0, 0, 0);
        }
        float bias = ldf(bo, t * 16 + l16, f32);
#pragma unroll
        for (int r = 0; r < 4; ++r) o[t][r] = acc[r] + bias;
    }

#pragma unroll
    for (int r = 0; r < 4; ++r) {
        float s1 = 0.f, s2 = 0.f;
#pragma unroll
        for (int t = 0; t < 8; ++t) { s1 += o[t][r]; s2 += o[t][r] * o[t][r]; }
#pragma unroll
        for (int off = 1; off <= 8; off <<= 1) {
            s1 += __shfl_xor(s1, off);
            s2 += __shfl_xor(s2, off);
        }
        float mu = s1 * (1.0f / OC);
        float var = fmaxf(s2 * (1.0f / OC) - mu * mu, 0.f);
        float rs = rsqrtf(var + 1e-5f);
        int node = rb + quad * 4 + r;
        if (node < NN) {
#pragma unroll
            for (int t = 0; t < 8; ++t) {
                int col = t * 16 + l16;
                float y = (o[t][r] - mu) * rs * ldf(gamma, col, f32) + ldf(beta, col, f32);
                if (f32) ((float*)out)[(size_t)node * OC + col] = y;
                else     ((bf16*)out)[(size_t)node * OC + col] = __float2bfloat16(y);
            }
        }
    }
}

// ---------------------------------------------------------------------------
extern "C" void kernel_launch(void* const* d_in, const int* in_sizes, int n_in,
                              void* d_out, int out_size, void* d_ws, size_t ws_size,
                              hipStream_t stream)
{
    int p = 0;
    const void* x   = d_in[p++];
    const void* eia = d_in[p++];
    const void* eib = eia;
    int split = 0;
    if (n_in >= 17) { eib = d_in[p++]; split = 1; }
    const void* Wq   = d_in[p++];
    const void* bq   = d_in[p++];
    const void* Wk   = d_in[p++];
    const void* bk   = d_in[p++];
    const void* Wv   = d_in[p++];
    const void* bv   = d_in[p++];
    const void* We1  = d_in[p++];
    const void* be1  = d_in[p++];
    const void* We2  = d_in[p++];
    const void* be2  = d_in[p++];
    const void* Wo   = d_in[p++];
    const void* bo   = d_in[p++];
    const void* gamma= d_in[p++];
    const void* beta = d_in[p++];
    const unsigned* gw = (const unsigned*)gamma;

    // workspace layout (~69 MB). cnt and ssum adjacent -> single memset.
    char* w = (char*)d_ws;
    bf16*  xb     = (bf16*)w;                  w += (size_t)NN * IC * 2;  // 6.4 MB
    unsigned char* qb_dst = (unsigned char*)w; w += (size_t)NN * 512;     // 25.6 MB (f16 q|b')
    unsigned char* ka_src = (unsigned char*)w; w += (size_t)NN * 512;     // 25.6 MB (f16 k|a)
    unsigned char* vf8    = (unsigned char*)w; w += (size_t)NN * OC;      // 6.4 MB
    int*   ssrc   = (int*)w;                   w += (size_t)NE * 4;       // 3.2 MB
    int*   cnt    = (int*)w;                   w += (size_t)NN * 4;       // 200 KB
    float* ssum   = (float*)w;                 w += 8 * 4;                // (memset w/ cnt)
    int*   rowptr = (int*)w;                   w += (size_t)(NN + 1) * 4;
    int*   cursor = (int*)w;                   w += (size_t)NN * 4;
    float* spart  = (float*)w;                 w += (size_t)NN * 4 * 4;   // 800 KB
    unsigned* We2h = (unsigned*)w;             w += 256 * 4;              // 1 KB
    float* be2f   = (float*)w;                 w += NH * 4;
    bf16*  WcatT  = (bf16*)w;                  w += (size_t)5 * OC * IC * 2;
    float* bcat   = (float*)w;                 w += 5 * OC * 4;
    bf16*  WoT    = (bf16*)w;                  w += (size_t)OC * OC * 2;

    if (ws_size < (size_t)((char*)w - (char*)d_ws)) return;

    hipMemsetAsync(cnt, 0, (size_t)NN * 4 + 32, stream);   // cnt + ssum
    prep<<<PB_X + PB_W + PB_WO + PB_CNT + 1, 256, 0, stream>>>(
        x, Wq, bq, Wk, bk, Wv, bv, We1, be1, We2, be2, Wo, gw,
        eia, eib, split,
        xb, WcatT, WoT, cnt, We2h, be2f, bcat);
    csr_scan<<<1, 1024, 0, stream>>>(cnt, rowptr, cursor);
    node_gemm<<<NG_GEMM + NG_FILL, 256, 0, stream>>>(
        xb, WcatT, bcat, qb_dst, ka_src, vf8, eia, eib, split, cursor, ssrc);
    edge_gather<<<NN / 4, 256, 0, stream>>>(rowptr, ssrc, qb_dst, ka_src, vf8,
                                            We2h, be2f, spart);
    s_reduce<<<SR_BLOCKS, 256, 0, stream>>>(spart, ssum);
    out_gemm<<<(NN + 63) / 64, 256, 0, stream>>>(qb_dst, WoT, bo, gamma, beta, gw,
                                                 ssum, d_out);
}